// Round 1
// baseline (422.653 us; speedup 1.0000x reference)
//
#include <hip/hip_runtime.h>

#define TSEQ 2048
#define CDIM 1024
#define HDIM 64
#define NROW (8 * 2048)

// ---------------- fused K/Q/V projection ----------------
// x:[16384,1024] @ {Wk,Wq,Wv}:[1024,64] -> kb,qb,vb:[16384,64]  (fp32)
// grid 256 blocks (64 rows each), block 256 threads, micro-tile 4 rows x 12 cols.
__global__ __launch_bounds__(256) void proj_kernel(
    const float* __restrict__ x,
    const float* __restrict__ Wk, const float* __restrict__ Wq, const float* __restrict__ Wv,
    float* __restrict__ kb, float* __restrict__ qb, float* __restrict__ vb)
{
    __shared__ float xs[32][68];   // [c][row]   transposed x chunk
    __shared__ float ws[32][196];  // [c][col]   col: 0..63=k, 64..127=q, 128..191=v
    const int t  = threadIdx.x;
    const int ty = t >> 4, tx = t & 15;
    const long rowbase = (long)blockIdx.x * 64;

    float acc[4][12];
    #pragma unroll
    for (int i = 0; i < 4; i++)
        #pragma unroll
        for (int j = 0; j < 12; j++) acc[i][j] = 0.f;

    for (int kc = 0; kc < CDIM; kc += 32) {
        __syncthreads();
        // stage x chunk (64 rows x 32 c), transposed store
        #pragma unroll
        for (int i = 0; i < 2; i++) {
            const int f = t + 256 * i;          // 0..511 float4 index
            const int r = f >> 3, cq = f & 7;   // 64 rows x 8 quads
            const float4 xv = *reinterpret_cast<const float4*>(&x[(rowbase + r) * CDIM + kc + 4 * cq]);
            xs[4*cq+0][r] = xv.x; xs[4*cq+1][r] = xv.y;
            xs[4*cq+2][r] = xv.z; xs[4*cq+3][r] = xv.w;
        }
        // stage W chunk: 3 mats x 32 c x 64 h
        #pragma unroll
        for (int i = 0; i < 6; i++) {
            const float* __restrict__ W = (i < 2) ? Wk : (i < 4) ? Wq : Wv;
            const int f = t + 256 * (i & 1);    // 0..511 within mat
            const int c = f >> 4, hq = f & 15;
            const float4 wv = *reinterpret_cast<const float4*>(&W[(kc + c) * HDIM + 4 * hq]);
            *reinterpret_cast<float4*>(&ws[c][(i >> 1) * 64 + 4 * hq]) = wv;
        }
        __syncthreads();
        #pragma unroll 4
        for (int c = 0; c < 32; c++) {
            const float4 a  = *reinterpret_cast<const float4*>(&xs[c][4 * ty]);
            const float4 b0 = *reinterpret_cast<const float4*>(&ws[c][12 * tx + 0]);
            const float4 b1 = *reinterpret_cast<const float4*>(&ws[c][12 * tx + 4]);
            const float4 b2 = *reinterpret_cast<const float4*>(&ws[c][12 * tx + 8]);
            const float av[4]  = {a.x, a.y, a.z, a.w};
            const float bv[12] = {b0.x,b0.y,b0.z,b0.w, b1.x,b1.y,b1.z,b1.w, b2.x,b2.y,b2.z,b2.w};
            #pragma unroll
            for (int i = 0; i < 4; i++)
                #pragma unroll
                for (int j = 0; j < 12; j++)
                    acc[i][j] += av[i] * bv[j];
        }
    }
    #pragma unroll
    for (int i = 0; i < 4; i++) {
        const long row = rowbase + 4 * ty + i;
        #pragma unroll
        for (int j = 0; j < 12; j++) {
            const int col = 12 * tx + j;
            float* const dst = (col < 64) ? kb : (col < 128) ? qb : vb;
            dst[row * HDIM + (col & 63)] = acc[i][j];
        }
    }
}

// ---------------- flash-style causal attention ----------------
// block = (b, 64-row q tile); key chunks of 64; online softmax; fp32 throughout.
__global__ __launch_bounds__(256) void attn_kernel(
    const float* __restrict__ kb, const float* __restrict__ qb, const float* __restrict__ vb,
    float* __restrict__ out)
{
    __shared__ float qs[64][68];  // [h][row], q*32 (exact pow2 scale fold)
    __shared__ float ks[64][68];  // [h][key] during scores; reused as ps[s][row] for PV
    __shared__ float vs[64][64];  // [s][h] natural (row-segment access only -> no pad needed)
    const int t  = threadIdx.x;
    const int ty = t >> 4, tx = t & 15;
    const int b  = blockIdx.x >> 5;
    const int qt = blockIdx.x & 31;
    const long gb = (long)b * TSEQ;
    const long rowbase = gb + (long)qt * 64;

    // stage q transposed, scaled by sqrt(C)=32
    #pragma unroll
    for (int i = 0; i < 4; i++) {
        const int f = t + 256 * i;
        const int r = f >> 4, hq = f & 15;
        const float4 qv = *reinterpret_cast<const float4*>(&qb[(rowbase + r) * HDIM + 4 * hq]);
        qs[4*hq+0][r] = 32.0f * qv.x; qs[4*hq+1][r] = 32.0f * qv.y;
        qs[4*hq+2][r] = 32.0f * qv.z; qs[4*hq+3][r] = 32.0f * qv.w;
    }

    float m[4], l[4], o[4][4];
    #pragma unroll
    for (int i = 0; i < 4; i++) {
        m[i] = -1e30f; l[i] = 0.f;
        #pragma unroll
        for (int j = 0; j < 4; j++) o[i][j] = 0.f;
    }

    for (int c = 0; c <= qt; c++) {
        __syncthreads();  // previous PV done; ks/vs free (also covers q staging at c==0)
        #pragma unroll
        for (int i = 0; i < 4; i++) {
            const int f = t + 256 * i;
            const int r = f >> 4, hq = f & 15;
            const long srow = gb + (long)c * 64 + r;
            const float4 kv = *reinterpret_cast<const float4*>(&kb[srow * HDIM + 4 * hq]);
            ks[4*hq+0][r] = kv.x; ks[4*hq+1][r] = kv.y;
            ks[4*hq+2][r] = kv.z; ks[4*hq+3][r] = kv.w;
            const float4 vv = *reinterpret_cast<const float4*>(&vb[srow * HDIM + 4 * hq]);
            *reinterpret_cast<float4*>(&vs[r][4 * hq]) = vv;
        }
        __syncthreads();

        // scores: S[4ty+i][4tx+j] over h
        float sc[4][4];
        #pragma unroll
        for (int i = 0; i < 4; i++)
            #pragma unroll
            for (int j = 0; j < 4; j++) sc[i][j] = 0.f;
        #pragma unroll 8
        for (int h = 0; h < 64; h++) {
            const float4 qa = *reinterpret_cast<const float4*>(&qs[h][4 * ty]);
            const float4 ka = *reinterpret_cast<const float4*>(&ks[h][4 * tx]);
            const float avq[4] = {qa.x, qa.y, qa.z, qa.w};
            const float avk[4] = {ka.x, ka.y, ka.z, ka.w};
            #pragma unroll
            for (int i = 0; i < 4; i++)
                #pragma unroll
                for (int j = 0; j < 4; j++)
                    sc[i][j] += avq[i] * avk[j];
        }
        if (c == qt) {  // diagonal chunk: mask key > row
            #pragma unroll
            for (int i = 0; i < 4; i++)
                #pragma unroll
                for (int j = 0; j < 4; j++)
                    if (4 * tx + j > 4 * ty + i) sc[i][j] = -1e30f;
        }

        // online softmax update (row reductions across tx lanes)
        float p[4][4];
        #pragma unroll
        for (int i = 0; i < 4; i++) {
            float mx = fmaxf(fmaxf(sc[i][0], sc[i][1]), fmaxf(sc[i][2], sc[i][3]));
            #pragma unroll
            for (int d = 1; d < 16; d <<= 1) mx = fmaxf(mx, __shfl_xor(mx, d));
            const float mnew = fmaxf(m[i], mx);
            const float corr = __expf(m[i] - mnew);
            m[i] = mnew;
            float rs = 0.f;
            #pragma unroll
            for (int j = 0; j < 4; j++) { p[i][j] = __expf(sc[i][j] - mnew); rs += p[i][j]; }
            l[i] = l[i] * corr + rs;
            #pragma unroll
            for (int j = 0; j < 4; j++) o[i][j] *= corr;
        }

        __syncthreads();  // everyone done reading ks before we overwrite it with P
        // P transposed into ks storage: ps[s][row]
        #pragma unroll
        for (int j = 0; j < 4; j++)
            #pragma unroll
            for (int i = 0; i < 4; i++)
                ks[4 * tx + j][4 * ty + i] = p[i][j];
        __syncthreads();  // P visible

        // PV: o[i][j] += sum_s P[row][s] * v[s][h]
        #pragma unroll 8
        for (int s = 0; s < 64; s++) {
            const float4 pr = *reinterpret_cast<const float4*>(&ks[s][4 * ty]);
            const float4 vv = *reinterpret_cast<const float4*>(&vs[s][4 * tx]);
            const float apv[4] = {pr.x, pr.y, pr.z, pr.w};
            const float avv[4] = {vv.x, vv.y, vv.z, vv.w};
            #pragma unroll
            for (int i = 0; i < 4; i++)
                #pragma unroll
                for (int j = 0; j < 4; j++)
                    o[i][j] += apv[i] * avv[j];
        }
    }

    // epilogue: total l across tx, normalize, store
    #pragma unroll
    for (int i = 0; i < 4; i++) {
        float li = l[i];
        #pragma unroll
        for (int d = 1; d < 16; d <<= 1) li += __shfl_xor(li, d);
        const float inv = 1.0f / li;
        const long row = rowbase + 4 * ty + i;
        float4 ov;
        ov.x = o[i][0] * inv; ov.y = o[i][1] * inv;
        ov.z = o[i][2] * inv; ov.w = o[i][3] * inv;
        *reinterpret_cast<float4*>(&out[row * HDIM + 4 * tx]) = ov;
    }
}

extern "C" void kernel_launch(void* const* d_in, const int* in_sizes, int n_in,
                              void* d_out, int out_size, void* d_ws, size_t ws_size,
                              hipStream_t stream) {
    const float* x  = (const float*)d_in[0];
    const float* Wk = (const float*)d_in[1];
    const float* Wq = (const float*)d_in[2];
    const float* Wv = (const float*)d_in[3];
    float* outp = (float*)d_out;

    float* kbuf = (float*)d_ws;
    float* qbuf = kbuf + (size_t)NROW * HDIM;
    float* vbuf = qbuf + (size_t)NROW * HDIM;

    proj_kernel<<<256, 256, 0, stream>>>(x, Wk, Wq, Wv, kbuf, qbuf, vbuf);
    attn_kernel<<<256, 256, 0, stream>>>(kbuf, qbuf, vbuf, outp);
}

// Round 2
// 172.932 us; speedup vs baseline: 2.4440x; 2.4440x over previous
//
#include <hip/hip_runtime.h>

#define TSEQ 2048
#define CDIM 1024
#define HDIM 64
#define NROW (8 * 2048)

typedef __attribute__((ext_vector_type(8))) short bf16x8;
typedef __attribute__((ext_vector_type(4))) float f32x4;

__device__ __forceinline__ unsigned short f2bf(float f) {
    unsigned int u = __builtin_bit_cast(unsigned int, f);
    u = (u + 0x7FFFu + ((u >> 16) & 1u)) >> 16;   // RNE, finite inputs only
    return (unsigned short)u;
}
__device__ __forceinline__ float bf2f(unsigned short h) {
    unsigned int u = ((unsigned int)h) << 16;
    return __builtin_bit_cast(float, u);
}
__device__ __forceinline__ void split2(float v, unsigned short& h, unsigned short& l) {
    h = f2bf(v);
    l = f2bf(v - bf2f(h));
}
__device__ __forceinline__ f32x4 mfma16(bf16x8 a, bf16x8 b, f32x4 c) {
    return __builtin_amdgcn_mfma_f32_16x16x32_bf16(a, b, c, 0, 0, 0);
}

// ---------------- W prep: transpose + hi/lo split ----------------
// Wk/Wq/Wv [1024][64] f32 -> wThi/wTlo [192][1024] bf16 (row n = output col, contiguous in c)
__global__ __launch_bounds__(256) void w_prep(
    const float* __restrict__ Wk, const float* __restrict__ Wq, const float* __restrict__ Wv,
    unsigned short* __restrict__ wThi, unsigned short* __restrict__ wTlo)
{
    __shared__ float tile[64][65];
    const int mm = blockIdx.x >> 4, kt = blockIdx.x & 15;
    const float* __restrict__ W = (mm == 0) ? Wk : (mm == 1) ? Wq : Wv;
    const int t = threadIdx.x;
    #pragma unroll
    for (int s = 0; s < 4; s++) {
        const int f = t + 256 * s;          // 1024 float4 = 64k x 64n tile
        const int r = f >> 4, cq = f & 15;
        const float4 wv = *reinterpret_cast<const float4*>(&W[(long)(kt * 64 + r) * HDIM + 4 * cq]);
        tile[4 * cq + 0][r] = wv.x; tile[4 * cq + 1][r] = wv.y;
        tile[4 * cq + 2][r] = wv.z; tile[4 * cq + 3][r] = wv.w;
    }
    __syncthreads();
    const int n = t >> 2, seg = t & 3;      // 64 cols x 4 segs of 16 k
    unsigned short hi[16], lo[16];
    #pragma unroll
    for (int u = 0; u < 16; u++) split2(tile[n][16 * seg + u], hi[u], lo[u]);
    const long base = (long)(mm * 64 + n) * CDIM + kt * 64 + 16 * seg;
    *reinterpret_cast<uint4*>(&wThi[base + 0]) = *reinterpret_cast<uint4*>(&hi[0]);
    *reinterpret_cast<uint4*>(&wThi[base + 8]) = *reinterpret_cast<uint4*>(&hi[8]);
    *reinterpret_cast<uint4*>(&wTlo[base + 0]) = *reinterpret_cast<uint4*>(&lo[0]);
    *reinterpret_cast<uint4*>(&wTlo[base + 8]) = *reinterpret_cast<uint4*>(&lo[8]);
}

// ---------------- fused K/Q/V projection (MFMA, split-bf16 x and W) ----------------
// emits khi/klo, qhi/qlo (x32 folded), vt (V transposed per batch: vt[b*64+h][t])
__global__ __launch_bounds__(256, 1) void proj_mfma(
    const float* __restrict__ x,
    const unsigned short* __restrict__ wThi, const unsigned short* __restrict__ wTlo,
    unsigned short* __restrict__ khi, unsigned short* __restrict__ klo,
    unsigned short* __restrict__ qhi, unsigned short* __restrict__ qlo,
    unsigned short* __restrict__ vt)
{
    __shared__ __align__(16) unsigned short xhi[64 * 40];  // 64 rows x 32 c, stride 40 (80B: 2-way banks)
    __shared__ __align__(16) unsigned short xlo[64 * 40];
    const int t = threadIdx.x;
    const int lane = t & 63, w = t >> 6;
    const int r15 = lane & 15, g = lane >> 4;
    const long rowbase = (long)blockIdx.x * 64;

    const int f0 = t, f1 = t + 256;
    const int r0 = f0 >> 3, c0 = f0 & 7;
    const int r1 = f1 >> 3, c1 = f1 & 7;

    f32x4 acc[4][3];
    #pragma unroll
    for (int mt = 0; mt < 4; mt++)
        #pragma unroll
        for (int nt = 0; nt < 3; nt++) acc[mt][nt] = (f32x4){0.f, 0.f, 0.f, 0.f};

    float4 xa0, xa1, xb0, xb1;
    xa0 = *reinterpret_cast<const float4*>(&x[(rowbase + r0) * CDIM + 4 * c0]);
    xa1 = *reinterpret_cast<const float4*>(&x[(rowbase + r1) * CDIM + 4 * c1]);

    for (int kc = 0; kc < CDIM; kc += 64) {
        // ---------- half A: chunk kc (xa), prefetch kc+32 ----------
        {
            ushort4 h4, l4;
            split2(xa0.x, h4.x, l4.x); split2(xa0.y, h4.y, l4.y);
            split2(xa0.z, h4.z, l4.z); split2(xa0.w, h4.w, l4.w);
            *reinterpret_cast<ushort4*>(&xhi[r0 * 40 + 4 * c0]) = h4;
            *reinterpret_cast<ushort4*>(&xlo[r0 * 40 + 4 * c0]) = l4;
            split2(xa1.x, h4.x, l4.x); split2(xa1.y, h4.y, l4.y);
            split2(xa1.z, h4.z, l4.z); split2(xa1.w, h4.w, l4.w);
            *reinterpret_cast<ushort4*>(&xhi[r1 * 40 + 4 * c1]) = h4;
            *reinterpret_cast<ushort4*>(&xlo[r1 * 40 + 4 * c1]) = l4;
        }
        bf16x8 bh[3], bl[3];
        #pragma unroll
        for (int nt = 0; nt < 3; nt++) {
            const long nrow = (long)(16 * (3 * w + nt) + r15) * CDIM;
            bh[nt] = *reinterpret_cast<const bf16x8*>(&wThi[nrow + kc + 8 * g]);
            bl[nt] = *reinterpret_cast<const bf16x8*>(&wTlo[nrow + kc + 8 * g]);
        }
        __syncthreads();
        xb0 = *reinterpret_cast<const float4*>(&x[(rowbase + r0) * CDIM + kc + 32 + 4 * c0]);
        xb1 = *reinterpret_cast<const float4*>(&x[(rowbase + r1) * CDIM + kc + 32 + 4 * c1]);
        {
            bf16x8 ah[4], al[4];
            #pragma unroll
            for (int mt = 0; mt < 4; mt++) {
                ah[mt] = *reinterpret_cast<const bf16x8*>(&xhi[(16 * mt + r15) * 40 + 8 * g]);
                al[mt] = *reinterpret_cast<const bf16x8*>(&xlo[(16 * mt + r15) * 40 + 8 * g]);
            }
            #pragma unroll
            for (int nt = 0; nt < 3; nt++)
                #pragma unroll
                for (int mt = 0; mt < 4; mt++) {
                    acc[mt][nt] = mfma16(ah[mt], bh[nt], acc[mt][nt]);
                    acc[mt][nt] = mfma16(al[mt], bh[nt], acc[mt][nt]);
                    acc[mt][nt] = mfma16(ah[mt], bl[nt], acc[mt][nt]);
                }
        }
        __syncthreads();
        // ---------- half B: chunk kc+32 (xb), prefetch kc+64 ----------
        {
            ushort4 h4, l4;
            split2(xb0.x, h4.x, l4.x); split2(xb0.y, h4.y, l4.y);
            split2(xb0.z, h4.z, l4.z); split2(xb0.w, h4.w, l4.w);
            *reinterpret_cast<ushort4*>(&xhi[r0 * 40 + 4 * c0]) = h4;
            *reinterpret_cast<ushort4*>(&xlo[r0 * 40 + 4 * c0]) = l4;
            split2(xb1.x, h4.x, l4.x); split2(xb1.y, h4.y, l4.y);
            split2(xb1.z, h4.z, l4.z); split2(xb1.w, h4.w, l4.w);
            *reinterpret_cast<ushort4*>(&xhi[r1 * 40 + 4 * c1]) = h4;
            *reinterpret_cast<ushort4*>(&xlo[r1 * 40 + 4 * c1]) = l4;
        }
        #pragma unroll
        for (int nt = 0; nt < 3; nt++) {
            const long nrow = (long)(16 * (3 * w + nt) + r15) * CDIM;
            bh[nt] = *reinterpret_cast<const bf16x8*>(&wThi[nrow + kc + 32 + 8 * g]);
            bl[nt] = *reinterpret_cast<const bf16x8*>(&wTlo[nrow + kc + 32 + 8 * g]);
        }
        __syncthreads();
        if (kc + 64 < CDIM) {
            xa0 = *reinterpret_cast<const float4*>(&x[(rowbase + r0) * CDIM + kc + 64 + 4 * c0]);
            xa1 = *reinterpret_cast<const float4*>(&x[(rowbase + r1) * CDIM + kc + 64 + 4 * c1]);
        }
        {
            bf16x8 ah[4], al[4];
            #pragma unroll
            for (int mt = 0; mt < 4; mt++) {
                ah[mt] = *reinterpret_cast<const bf16x8*>(&xhi[(16 * mt + r15) * 40 + 8 * g]);
                al[mt] = *reinterpret_cast<const bf16x8*>(&xlo[(16 * mt + r15) * 40 + 8 * g]);
            }
            #pragma unroll
            for (int nt = 0; nt < 3; nt++)
                #pragma unroll
                for (int mt = 0; mt < 4; mt++) {
                    acc[mt][nt] = mfma16(ah[mt], bh[nt], acc[mt][nt]);
                    acc[mt][nt] = mfma16(al[mt], bh[nt], acc[mt][nt]);
                    acc[mt][nt] = mfma16(ah[mt], bl[nt], acc[mt][nt]);
                }
        }
        __syncthreads();
    }

    // epilogue: split + store. D(m,n): row = 16mt+4g+reg, col = 16*(3w+nt)+r15
    const int bb = (int)(rowbase >> 11);
    const int trow0 = (int)(rowbase & 2047);
    #pragma unroll
    for (int nt = 0; nt < 3; nt++) {
        const int ntg = 3 * w + nt;
        const int mat = ntg >> 2;
        const int colin = (ntg & 3) * 16 + r15;
        if (mat == 0) {
            #pragma unroll
            for (int mt = 0; mt < 4; mt++)
                #pragma unroll
                for (int reg = 0; reg < 4; reg++) {
                    const float v = acc[mt][nt][reg];
                    unsigned short h, l;
                    split2(v, h, l);
                    const long idx = (rowbase + 16 * mt + 4 * g + reg) * HDIM + colin;
                    khi[idx] = h; klo[idx] = l;
                }
        } else if (mat == 1) {
            #pragma unroll
            for (int mt = 0; mt < 4; mt++)
                #pragma unroll
                for (int reg = 0; reg < 4; reg++) {
                    const float v = acc[mt][nt][reg] * 32.0f;   // fold sqrt(C): exact pow2
                    unsigned short h, l;
                    split2(v, h, l);
                    const long idx = (rowbase + 16 * mt + 4 * g + reg) * HDIM + colin;
                    qhi[idx] = h; qlo[idx] = l;
                }
        } else {
            #pragma unroll
            for (int mt = 0; mt < 4; mt++) {
                ushort4 pk;
                pk.x = f2bf(acc[mt][nt][0]); pk.y = f2bf(acc[mt][nt][1]);
                pk.z = f2bf(acc[mt][nt][2]); pk.w = f2bf(acc[mt][nt][3]);
                const long idx = ((long)bb * 64 + colin) * TSEQ + trow0 + 16 * mt + 4 * g;
                *reinterpret_cast<ushort4*>(&vt[idx]) = pk;
            }
        }
    }
}

// ---------------- MFMA flash attention: 1 wave per 16-row q-tile, no barriers ----------------
// S^T = mfma(K, Q^T): lane owns q-col = lane&15 -> m,l are per-lane scalars.
// PV: out^T = mfma(V^T, P^T), P via 2.3KB wave-private LDS roundtrip.
__global__ __launch_bounds__(64) void attn_mfma(
    const unsigned short* __restrict__ khi, const unsigned short* __restrict__ klo,
    const unsigned short* __restrict__ qhi, const unsigned short* __restrict__ qlo,
    const unsigned short* __restrict__ vt, float* __restrict__ out)
{
    __shared__ __align__(16) unsigned short p_lds[16 * 72];  // [q][key] stride 72 (144B: 2-way banks)
    const int l = threadIdx.x;
    const int r15 = l & 15, g = l >> 4;
    const int wid = blockIdx.x;
    const int b = wid >> 7, i = wid & 127;
    const long qrow = (long)b * TSEQ + 16 * i + r15;

    bf16x8 Qh[2], Ql[2];
    #pragma unroll
    for (int ks = 0; ks < 2; ks++) {
        Qh[ks] = *reinterpret_cast<const bf16x8*>(&qhi[qrow * HDIM + 32 * ks + 8 * g]);
        Ql[ks] = *reinterpret_cast<const bf16x8*>(&qlo[qrow * HDIM + 32 * ks + 8 * g]);
    }

    f32x4 o[4];
    #pragma unroll
    for (int ht = 0; ht < 4; ht++) o[ht] = (f32x4){0.f, 0.f, 0.f, 0.f};
    float m = -3e38f, lsum = 0.f;
    const int nkb = (i >> 2) + 1;

    for (int kb = 0; kb < nkb; kb++) {
        const long keyrow = (long)b * TSEQ + kb * 64;
        f32x4 sc[4];
        #pragma unroll
        for (int mt = 0; mt < 4; mt++) {
            f32x4 s = (f32x4){0.f, 0.f, 0.f, 0.f};
            const int ktile = 4 * kb + mt;
            if (ktile <= i) {
                const long arow = (keyrow + 16 * mt + r15) * HDIM;
                #pragma unroll
                for (int ks = 0; ks < 2; ks++) {
                    const bf16x8 ah = *reinterpret_cast<const bf16x8*>(&khi[arow + 32 * ks + 8 * g]);
                    const bf16x8 al = *reinterpret_cast<const bf16x8*>(&klo[arow + 32 * ks + 8 * g]);
                    s = mfma16(ah, Qh[ks], s);
                    s = mfma16(ah, Ql[ks], s);
                    s = mfma16(al, Qh[ks], s);
                }
                if (ktile == i) {   // diagonal tile: mask key_local > q_local
                    #pragma unroll
                    for (int reg = 0; reg < 4; reg++)
                        if (4 * g + reg > r15) s[reg] = -1e30f;
                }
            }
            sc[mt] = s;
        }
        // online softmax (per-lane q-column; butterfly over lanes {q, q+16, q+32, q+48})
        float bm = -3e38f;
        #pragma unroll
        for (int mt = 0; mt < 4; mt++)
            if (4 * kb + mt <= i)
                bm = fmaxf(bm, fmaxf(fmaxf(sc[mt][0], sc[mt][1]), fmaxf(sc[mt][2], sc[mt][3])));
        bm = fmaxf(bm, __shfl_xor(bm, 16));
        bm = fmaxf(bm, __shfl_xor(bm, 32));
        const float mnew = fmaxf(m, bm);
        const float corr = __expf(m - mnew);
        m = mnew;
        float rs = 0.f;
        #pragma unroll
        for (int mt = 0; mt < 4; mt++) {
            ushort4 pk = {0, 0, 0, 0};
            if (4 * kb + mt <= i) {
                const float p0 = __expf(sc[mt][0] - mnew);
                const float p1 = __expf(sc[mt][1] - mnew);
                const float p2 = __expf(sc[mt][2] - mnew);
                const float p3 = __expf(sc[mt][3] - mnew);
                rs += (p0 + p1) + (p2 + p3);
                pk.x = f2bf(p0); pk.y = f2bf(p1); pk.z = f2bf(p2); pk.w = f2bf(p3);
            }
            *reinterpret_cast<ushort4*>(&p_lds[r15 * 72 + 16 * mt + 4 * g]) = pk;
        }
        rs += __shfl_xor(rs, 16);
        rs += __shfl_xor(rs, 32);
        lsum = lsum * corr + rs;
        #pragma unroll
        for (int ht = 0; ht < 4; ht++) o[ht] *= corr;
        // PV (lgkmcnt ordering within the single wave covers the LDS roundtrip)
        #pragma unroll
        for (int ks = 0; ks < 2; ks++) {
            const bf16x8 pb = *reinterpret_cast<const bf16x8*>(&p_lds[r15 * 72 + 32 * ks + 8 * g]);
            #pragma unroll
            for (int ht = 0; ht < 4; ht++) {
                const bf16x8 av = *reinterpret_cast<const bf16x8*>(
                    &vt[((long)b * 64 + 16 * ht + r15) * TSEQ + kb * 64 + 32 * ks + 8 * g]);
                o[ht] = mfma16(av, pb, o[ht]);
            }
        }
    }

    const float inv = 1.0f / lsum;
    #pragma unroll
    for (int ht = 0; ht < 4; ht++) {
        const f32x4 ov = o[ht] * inv;
        *reinterpret_cast<f32x4*>(&out[qrow * HDIM + 16 * ht + 4 * g]) = ov;
    }
}

extern "C" void kernel_launch(void* const* d_in, const int* in_sizes, int n_in,
                              void* d_out, int out_size, void* d_ws, size_t ws_size,
                              hipStream_t stream) {
    const float* x  = (const float*)d_in[0];
    const float* Wk = (const float*)d_in[1];
    const float* Wq = (const float*)d_in[2];
    const float* Wv = (const float*)d_in[3];
    float* outp = (float*)d_out;

    const size_t SZ = (size_t)NROW * HDIM;          // 1,048,576 elems
    unsigned short* ws   = (unsigned short*)d_ws;
    unsigned short* khi  = ws;
    unsigned short* klo  = ws + 1 * SZ;
    unsigned short* qhi  = ws + 2 * SZ;
    unsigned short* qlo  = ws + 3 * SZ;
    unsigned short* vt   = ws + 4 * SZ;
    unsigned short* wThi = ws + 5 * SZ;
    unsigned short* wTlo = ws + 5 * SZ + 192 * 1024;

    w_prep<<<48, 256, 0, stream>>>(Wk, Wq, Wv, wThi, wTlo);
    proj_mfma<<<256, 256, 0, stream>>>(x, wThi, wTlo, khi, klo, qhi, qlo, vt);
    attn_mfma<<<1024, 64, 0, stream>>>(khi, klo, qhi, qlo, vt, outp);
}

// Round 3
// 144.351 us; speedup vs baseline: 2.9279x; 1.1980x over previous
//
#include <hip/hip_runtime.h>

#define TSEQ 2048
#define CDIM 1024
#define HDIM 64
#define NROW (8 * 2048)

typedef __attribute__((ext_vector_type(8))) short bf16x8;
typedef __attribute__((ext_vector_type(4))) float f32x4;

__device__ __forceinline__ unsigned short f2bf(float f) {
    unsigned int u = __builtin_bit_cast(unsigned int, f);
    u = (u + 0x7FFFu + ((u >> 16) & 1u)) >> 16;   // RNE, finite inputs only
    return (unsigned short)u;
}
__device__ __forceinline__ float bf2f(unsigned short h) {
    unsigned int u = ((unsigned int)h) << 16;
    return __builtin_bit_cast(float, u);
}
__device__ __forceinline__ void split2(float v, unsigned short& h, unsigned short& l) {
    h = f2bf(v);
    l = f2bf(v - bf2f(h));
}
__device__ __forceinline__ f32x4 mfma16(bf16x8 a, bf16x8 b, f32x4 c) {
    return __builtin_amdgcn_mfma_f32_16x16x32_bf16(a, b, c, 0, 0, 0);
}

// ---------------- W prep: transpose + hi/lo split ----------------
__global__ __launch_bounds__(256) void w_prep(
    const float* __restrict__ Wk, const float* __restrict__ Wq, const float* __restrict__ Wv,
    unsigned short* __restrict__ wThi, unsigned short* __restrict__ wTlo)
{
    __shared__ float tile[64][65];
    const int mm = blockIdx.x >> 4, kt = blockIdx.x & 15;
    const float* __restrict__ W = (mm == 0) ? Wk : (mm == 1) ? Wq : Wv;
    const int t = threadIdx.x;
    #pragma unroll
    for (int s = 0; s < 4; s++) {
        const int f = t + 256 * s;
        const int r = f >> 4, cq = f & 15;
        const float4 wv = *reinterpret_cast<const float4*>(&W[(long)(kt * 64 + r) * HDIM + 4 * cq]);
        tile[4 * cq + 0][r] = wv.x; tile[4 * cq + 1][r] = wv.y;
        tile[4 * cq + 2][r] = wv.z; tile[4 * cq + 3][r] = wv.w;
    }
    __syncthreads();
    const int n = t >> 2, seg = t & 3;
    unsigned short hi[16], lo[16];
    #pragma unroll
    for (int u = 0; u < 16; u++) split2(tile[n][16 * seg + u], hi[u], lo[u]);
    const long base = (long)(mm * 64 + n) * CDIM + kt * 64 + 16 * seg;
    *reinterpret_cast<uint4*>(&wThi[base + 0]) = *reinterpret_cast<uint4*>(&hi[0]);
    *reinterpret_cast<uint4*>(&wThi[base + 8]) = *reinterpret_cast<uint4*>(&hi[8]);
    *reinterpret_cast<uint4*>(&wTlo[base + 0]) = *reinterpret_cast<uint4*>(&lo[0]);
    *reinterpret_cast<uint4*>(&wTlo[base + 8]) = *reinterpret_cast<uint4*>(&lo[8]);
}

// ---------------- fused K/Q/V projection (32-row tiles, 512 blocks) ----------------
__global__ __launch_bounds__(256, 1) void proj_mfma(
    const float* __restrict__ x,
    const unsigned short* __restrict__ wThi, const unsigned short* __restrict__ wTlo,
    unsigned short* __restrict__ khi, unsigned short* __restrict__ klo,
    unsigned short* __restrict__ qhi, unsigned short* __restrict__ qlo,
    unsigned short* __restrict__ vt)
{
    __shared__ __align__(16) unsigned short xhi[32 * 40];
    __shared__ __align__(16) unsigned short xlo[32 * 40];
    const int t = threadIdx.x;
    const int lane = t & 63, w = t >> 6;
    const int r15 = lane & 15, g = lane >> 4;
    const long rowbase = (long)blockIdx.x * 32;
    const int r0 = t >> 3, c0 = t & 7;

    f32x4 acc[2][3];
    #pragma unroll
    for (int mt = 0; mt < 2; mt++)
        #pragma unroll
        for (int nt = 0; nt < 3; nt++) acc[mt][nt] = (f32x4){0.f, 0.f, 0.f, 0.f};

    float4 xa, xb;
    xa = *reinterpret_cast<const float4*>(&x[(rowbase + r0) * CDIM + 4 * c0]);

    for (int kc = 0; kc < CDIM; kc += 64) {
        // ---------- half A ----------
        {
            ushort4 h4, l4;
            split2(xa.x, h4.x, l4.x); split2(xa.y, h4.y, l4.y);
            split2(xa.z, h4.z, l4.z); split2(xa.w, h4.w, l4.w);
            *reinterpret_cast<ushort4*>(&xhi[r0 * 40 + 4 * c0]) = h4;
            *reinterpret_cast<ushort4*>(&xlo[r0 * 40 + 4 * c0]) = l4;
        }
        bf16x8 bh[3], bl[3];
        #pragma unroll
        for (int nt = 0; nt < 3; nt++) {
            const long nrow = (long)(16 * (3 * w + nt) + r15) * CDIM;
            bh[nt] = *reinterpret_cast<const bf16x8*>(&wThi[nrow + kc + 8 * g]);
            bl[nt] = *reinterpret_cast<const bf16x8*>(&wTlo[nrow + kc + 8 * g]);
        }
        __syncthreads();
        xb = *reinterpret_cast<const float4*>(&x[(rowbase + r0) * CDIM + kc + 32 + 4 * c0]);
        {
            bf16x8 ah[2], al[2];
            #pragma unroll
            for (int mt = 0; mt < 2; mt++) {
                ah[mt] = *reinterpret_cast<const bf16x8*>(&xhi[(16 * mt + r15) * 40 + 8 * g]);
                al[mt] = *reinterpret_cast<const bf16x8*>(&xlo[(16 * mt + r15) * 40 + 8 * g]);
            }
            #pragma unroll
            for (int nt = 0; nt < 3; nt++)
                #pragma unroll
                for (int mt = 0; mt < 2; mt++) {
                    acc[mt][nt] = mfma16(ah[mt], bh[nt], acc[mt][nt]);
                    acc[mt][nt] = mfma16(al[mt], bh[nt], acc[mt][nt]);
                    acc[mt][nt] = mfma16(ah[mt], bl[nt], acc[mt][nt]);
                }
        }
        __syncthreads();
        // ---------- half B ----------
        {
            ushort4 h4, l4;
            split2(xb.x, h4.x, l4.x); split2(xb.y, h4.y, l4.y);
            split2(xb.z, h4.z, l4.z); split2(xb.w, h4.w, l4.w);
            *reinterpret_cast<ushort4*>(&xhi[r0 * 40 + 4 * c0]) = h4;
            *reinterpret_cast<ushort4*>(&xlo[r0 * 40 + 4 * c0]) = l4;
        }
        #pragma unroll
        for (int nt = 0; nt < 3; nt++) {
            const long nrow = (long)(16 * (3 * w + nt) + r15) * CDIM;
            bh[nt] = *reinterpret_cast<const bf16x8*>(&wThi[nrow + kc + 32 + 8 * g]);
            bl[nt] = *reinterpret_cast<const bf16x8*>(&wTlo[nrow + kc + 32 + 8 * g]);
        }
        __syncthreads();
        if (kc + 64 < CDIM) {
            xa = *reinterpret_cast<const float4*>(&x[(rowbase + r0) * CDIM + kc + 64 + 4 * c0]);
        }
        {
            bf16x8 ah[2], al[2];
            #pragma unroll
            for (int mt = 0; mt < 2; mt++) {
                ah[mt] = *reinterpret_cast<const bf16x8*>(&xhi[(16 * mt + r15) * 40 + 8 * g]);
                al[mt] = *reinterpret_cast<const bf16x8*>(&xlo[(16 * mt + r15) * 40 + 8 * g]);
            }
            #pragma unroll
            for (int nt = 0; nt < 3; nt++)
                #pragma unroll
                for (int mt = 0; mt < 2; mt++) {
                    acc[mt][nt] = mfma16(ah[mt], bh[nt], acc[mt][nt]);
                    acc[mt][nt] = mfma16(al[mt], bh[nt], acc[mt][nt]);
                    acc[mt][nt] = mfma16(ah[mt], bl[nt], acc[mt][nt]);
                }
        }
        __syncthreads();
    }

    const int bb = (int)(rowbase >> 11);
    const int trow0 = (int)(rowbase & 2047);
    #pragma unroll
    for (int nt = 0; nt < 3; nt++) {
        const int ntg = 3 * w + nt;
        const int mat = ntg >> 2;
        const int colin = (ntg & 3) * 16 + r15;
        if (mat == 0) {
            #pragma unroll
            for (int mt = 0; mt < 2; mt++)
                #pragma unroll
                for (int reg = 0; reg < 4; reg++) {
                    unsigned short h, l;
                    split2(acc[mt][nt][reg], h, l);
                    const long idx = (rowbase + 16 * mt + 4 * g + reg) * HDIM + colin;
                    khi[idx] = h; klo[idx] = l;
                }
        } else if (mat == 1) {
            #pragma unroll
            for (int mt = 0; mt < 2; mt++)
                #pragma unroll
                for (int reg = 0; reg < 4; reg++) {
                    unsigned short h, l;
                    split2(acc[mt][nt][reg] * 32.0f, h, l);   // fold sqrt(C): exact pow2
                    const long idx = (rowbase + 16 * mt + 4 * g + reg) * HDIM + colin;
                    qhi[idx] = h; qlo[idx] = l;
                }
        } else {
            #pragma unroll
            for (int mt = 0; mt < 2; mt++) {
                ushort4 pk;
                pk.x = f2bf(acc[mt][nt][0]); pk.y = f2bf(acc[mt][nt][1]);
                pk.z = f2bf(acc[mt][nt][2]); pk.w = f2bf(acc[mt][nt][3]);
                const long idx = ((long)bb * 64 + colin) * TSEQ + trow0 + 16 * mt + 4 * g;
                *reinterpret_cast<ushort4*>(&vt[idx]) = pk;
            }
        }
    }
}

// ---------------- attention helpers ----------------
__device__ __forceinline__ void kload8(
    const unsigned short* __restrict__ khi, const unsigned short* __restrict__ klo,
    long keybase, int r15, int g, bf16x8 (&kh)[8], bf16x8 (&kl)[8])
{
    #pragma unroll
    for (int mt = 0; mt < 4; mt++) {
        const long arow = (keybase + 16 * mt + r15) * HDIM + 8 * g;
        #pragma unroll
        for (int ks = 0; ks < 2; ks++) {
            kh[2 * mt + ks] = *reinterpret_cast<const bf16x8*>(&khi[arow + 32 * ks]);
            kl[2 * mt + ks] = *reinterpret_cast<const bf16x8*>(&klo[arow + 32 * ks]);
        }
    }
}

// full (unmasked) chunk: compute with cur K, prefetch next K into (nh,nl)
__device__ __forceinline__ void chunk_full(
    const bf16x8 (&kh)[8], const bf16x8 (&kl)[8],
    bf16x8 (&nh)[8], bf16x8 (&nl)[8],
    const bf16x8 (&Qh)[2], const bf16x8 (&Ql)[2],
    const unsigned short* __restrict__ khi, const unsigned short* __restrict__ klo,
    const unsigned short* __restrict__ vt,
    long bkey, int b, int kb, int r15, int g,
    unsigned short* __restrict__ p_lds,
    float& m, float& lsum, f32x4 (&o)[4])
{
    bf16x8 Vv[8];
    #pragma unroll
    for (int ht = 0; ht < 4; ht++)
        #pragma unroll
        for (int ks = 0; ks < 2; ks++)
            Vv[2 * ht + ks] = *reinterpret_cast<const bf16x8*>(
                &vt[((long)b * 64 + 16 * ht + r15) * TSEQ + kb * 64 + 32 * ks + 8 * g]);
    kload8(khi, klo, bkey + (long)(kb + 1) * 64, r15, g, nh, nl);

    f32x4 sc[4];
    #pragma unroll
    for (int mt = 0; mt < 4; mt++) {
        f32x4 s = (f32x4){0.f, 0.f, 0.f, 0.f};
        #pragma unroll
        for (int ks = 0; ks < 2; ks++) {
            s = mfma16(kh[2 * mt + ks], Qh[ks], s);
            s = mfma16(kh[2 * mt + ks], Ql[ks], s);
            s = mfma16(kl[2 * mt + ks], Qh[ks], s);
        }
        sc[mt] = s;
    }

    float bm = -3e38f;
    #pragma unroll
    for (int mt = 0; mt < 4; mt++)
        bm = fmaxf(bm, fmaxf(fmaxf(sc[mt][0], sc[mt][1]), fmaxf(sc[mt][2], sc[mt][3])));
    bm = fmaxf(bm, __shfl_xor(bm, 16));
    bm = fmaxf(bm, __shfl_xor(bm, 32));
    const float mnew = fmaxf(m, bm);
    const float corr = __expf(m - mnew);
    m = mnew;
    float rs = 0.f;
    #pragma unroll
    for (int mt = 0; mt < 4; mt++) {
        const float p0 = __expf(sc[mt][0] - mnew);
        const float p1 = __expf(sc[mt][1] - mnew);
        const float p2 = __expf(sc[mt][2] - mnew);
        const float p3 = __expf(sc[mt][3] - mnew);
        rs += (p0 + p1) + (p2 + p3);
        ushort4 pk;
        pk.x = f2bf(p0); pk.y = f2bf(p1); pk.z = f2bf(p2); pk.w = f2bf(p3);
        *reinterpret_cast<ushort4*>(&p_lds[r15 * 72 + 16 * mt + 4 * g]) = pk;
    }
    rs += __shfl_xor(rs, 16);
    rs += __shfl_xor(rs, 32);
    lsum = lsum * corr + rs;
    #pragma unroll
    for (int ht = 0; ht < 4; ht++) o[ht] *= corr;
    #pragma unroll
    for (int ks = 0; ks < 2; ks++) {
        const bf16x8 pb = *reinterpret_cast<const bf16x8*>(&p_lds[r15 * 72 + 32 * ks + 8 * g]);
        #pragma unroll
        for (int ht = 0; ht < 4; ht++) o[ht] = mfma16(Vv[2 * ht + ks], pb, o[ht]);
    }
}

// final (diagonal) chunk: per-mt validity + diagonal mask, no prefetch
__device__ __forceinline__ void chunk_final(
    const bf16x8 (&kh)[8], const bf16x8 (&kl)[8],
    const bf16x8 (&Qh)[2], const bf16x8 (&Ql)[2],
    const unsigned short* __restrict__ vt,
    int b, int kb, int i, int r15, int g,
    unsigned short* __restrict__ p_lds,
    float& m, float& lsum, f32x4 (&o)[4])
{
    const int rem = i & 3;
    bf16x8 Vv[8];
    #pragma unroll
    for (int ht = 0; ht < 4; ht++)
        #pragma unroll
        for (int ks = 0; ks < 2; ks++)
            Vv[2 * ht + ks] = *reinterpret_cast<const bf16x8*>(
                &vt[((long)b * 64 + 16 * ht + r15) * TSEQ + kb * 64 + 32 * ks + 8 * g]);

    f32x4 sc[4];
    #pragma unroll
    for (int mt = 0; mt < 4; mt++) {
        f32x4 s = (f32x4){0.f, 0.f, 0.f, 0.f};
        if (mt <= rem) {
            #pragma unroll
            for (int ks = 0; ks < 2; ks++) {
                s = mfma16(kh[2 * mt + ks], Qh[ks], s);
                s = mfma16(kh[2 * mt + ks], Ql[ks], s);
                s = mfma16(kl[2 * mt + ks], Qh[ks], s);
            }
            if (mt == rem) {
                #pragma unroll
                for (int reg = 0; reg < 4; reg++)
                    if (4 * g + reg > r15) s[reg] = -1e30f;
            }
        }
        sc[mt] = s;
    }

    float bm = -3e38f;
    #pragma unroll
    for (int mt = 0; mt < 4; mt++)
        if (mt <= rem)
            bm = fmaxf(bm, fmaxf(fmaxf(sc[mt][0], sc[mt][1]), fmaxf(sc[mt][2], sc[mt][3])));
    bm = fmaxf(bm, __shfl_xor(bm, 16));
    bm = fmaxf(bm, __shfl_xor(bm, 32));
    const float mnew = fmaxf(m, bm);
    const float corr = __expf(m - mnew);
    m = mnew;
    float rs = 0.f;
    #pragma unroll
    for (int mt = 0; mt < 4; mt++) {
        ushort4 pk = {0, 0, 0, 0};
        if (mt <= rem) {
            const float p0 = __expf(sc[mt][0] - mnew);
            const float p1 = __expf(sc[mt][1] - mnew);
            const float p2 = __expf(sc[mt][2] - mnew);
            const float p3 = __expf(sc[mt][3] - mnew);
            rs += (p0 + p1) + (p2 + p3);
            pk.x = f2bf(p0); pk.y = f2bf(p1); pk.z = f2bf(p2); pk.w = f2bf(p3);
        }
        *reinterpret_cast<ushort4*>(&p_lds[r15 * 72 + 16 * mt + 4 * g]) = pk;
    }
    rs += __shfl_xor(rs, 16);
    rs += __shfl_xor(rs, 32);
    lsum = lsum * corr + rs;
    #pragma unroll
    for (int ht = 0; ht < 4; ht++) o[ht] *= corr;
    #pragma unroll
    for (int ks = 0; ks < 2; ks++) {
        const bf16x8 pb = *reinterpret_cast<const bf16x8*>(&p_lds[r15 * 72 + 32 * ks + 8 * g]);
        #pragma unroll
        for (int ht = 0; ht < 4; ht++) o[ht] = mfma16(Vv[2 * ht + ks], pb, o[ht]);
    }
}

// ---------------- MFMA flash attention: 1 wave per 16-row q-tile, reg-pipelined ----------------
__global__ __launch_bounds__(64, 1) void attn_mfma(
    const unsigned short* __restrict__ khi, const unsigned short* __restrict__ klo,
    const unsigned short* __restrict__ qhi, const unsigned short* __restrict__ qlo,
    const unsigned short* __restrict__ vt, float* __restrict__ out)
{
    __shared__ __align__(16) unsigned short p_lds[16 * 72];
    const int l = threadIdx.x;
    const int r15 = l & 15, g = l >> 4;
    const int wid = blockIdx.x;
    const int b = wid >> 7, i = wid & 127;
    const long bkey = (long)b * TSEQ;
    const long qrow = bkey + 16 * i + r15;

    bf16x8 Qh[2], Ql[2];
    #pragma unroll
    for (int ks = 0; ks < 2; ks++) {
        Qh[ks] = *reinterpret_cast<const bf16x8*>(&qhi[qrow * HDIM + 32 * ks + 8 * g]);
        Ql[ks] = *reinterpret_cast<const bf16x8*>(&qlo[qrow * HDIM + 32 * ks + 8 * g]);
    }

    f32x4 o[4];
    #pragma unroll
    for (int ht = 0; ht < 4; ht++) o[ht] = (f32x4){0.f, 0.f, 0.f, 0.f};
    float m = -3e38f, lsum = 0.f;
    const int lc = i >> 2;

    bf16x8 KAh[8], KAl[8], KBh[8], KBl[8];
    kload8(khi, klo, bkey, r15, g, KAh, KAl);

    int kb = 0;
    while (true) {
        if (kb == lc) {
            chunk_final(KAh, KAl, Qh, Ql, vt, b, kb, i, r15, g, p_lds, m, lsum, o);
            break;
        }
        chunk_full(KAh, KAl, KBh, KBl, Qh, Ql, khi, klo, vt, bkey, b, kb, r15, g, p_lds, m, lsum, o);
        kb++;
        if (kb == lc) {
            chunk_final(KBh, KBl, Qh, Ql, vt, b, kb, i, r15, g, p_lds, m, lsum, o);
            break;
        }
        chunk_full(KBh, KBl, KAh, KAl, Qh, Ql, khi, klo, vt, bkey, b, kb, r15, g, p_lds, m, lsum, o);
        kb++;
    }

    const float inv = 1.0f / lsum;
    #pragma unroll
    for (int ht = 0; ht < 4; ht++) {
        const f32x4 ov = o[ht] * inv;
        *reinterpret_cast<f32x4*>(&out[qrow * HDIM + 16 * ht + 4 * g]) = ov;
    }
}

extern "C" void kernel_launch(void* const* d_in, const int* in_sizes, int n_in,
                              void* d_out, int out_size, void* d_ws, size_t ws_size,
                              hipStream_t stream) {
    const float* x  = (const float*)d_in[0];
    const float* Wk = (const float*)d_in[1];
    const float* Wq = (const float*)d_in[2];
    const float* Wv = (const float*)d_in[3];
    float* outp = (float*)d_out;

    const size_t SZ = (size_t)NROW * HDIM;
    unsigned short* ws   = (unsigned short*)d_ws;
    unsigned short* khi  = ws;
    unsigned short* klo  = ws + 1 * SZ;
    unsigned short* qhi  = ws + 2 * SZ;
    unsigned short* qlo  = ws + 3 * SZ;
    unsigned short* vt   = ws + 4 * SZ;
    unsigned short* wThi = ws + 5 * SZ;
    unsigned short* wTlo = ws + 5 * SZ + 192 * 1024;

    w_prep<<<48, 256, 0, stream>>>(Wk, Wq, Wv, wThi, wTlo);
    proj_mfma<<<512, 256, 0, stream>>>(x, wThi, wTlo, khi, klo, qhi, qlo, vt);
    attn_mfma<<<1024, 64, 0, stream>>>(khi, klo, qhi, qlo, vt, outp);
}

// Round 4
// 137.876 us; speedup vs baseline: 3.0654x; 1.0470x over previous
//
#include <hip/hip_runtime.h>

#define TSEQ 2048
#define CDIM 1024
#define HDIM 64
#define NROW (8 * 2048)

typedef __attribute__((ext_vector_type(8))) short bf16x8;
typedef __attribute__((ext_vector_type(4))) float f32x4;

__device__ __forceinline__ unsigned short f2bf(float f) {
    unsigned int u = __builtin_bit_cast(unsigned int, f);
    u = (u + 0x7FFFu + ((u >> 16) & 1u)) >> 16;   // RNE, finite inputs only
    return (unsigned short)u;
}
__device__ __forceinline__ float bf2f(unsigned short h) {
    unsigned int u = ((unsigned int)h) << 16;
    return __builtin_bit_cast(float, u);
}
__device__ __forceinline__ void split2(float v, unsigned short& h, unsigned short& l) {
    h = f2bf(v);
    l = f2bf(v - bf2f(h));
}
__device__ __forceinline__ f32x4 mfma16(bf16x8 a, bf16x8 b, f32x4 c) {
    return __builtin_amdgcn_mfma_f32_16x16x32_bf16(a, b, c, 0, 0, 0);
}

// ---------------- W prep: transpose + hi/lo split ----------------
__global__ __launch_bounds__(256) void w_prep(
    const float* __restrict__ Wk, const float* __restrict__ Wq, const float* __restrict__ Wv,
    unsigned short* __restrict__ wThi, unsigned short* __restrict__ wTlo)
{
    __shared__ float tile[64][65];
    const int mm = blockIdx.x >> 4, kt = blockIdx.x & 15;
    const float* __restrict__ W = (mm == 0) ? Wk : (mm == 1) ? Wq : Wv;
    const int t = threadIdx.x;
    #pragma unroll
    for (int s = 0; s < 4; s++) {
        const int f = t + 256 * s;
        const int r = f >> 4, cq = f & 15;
        const float4 wv = *reinterpret_cast<const float4*>(&W[(long)(kt * 64 + r) * HDIM + 4 * cq]);
        tile[4 * cq + 0][r] = wv.x; tile[4 * cq + 1][r] = wv.y;
        tile[4 * cq + 2][r] = wv.z; tile[4 * cq + 3][r] = wv.w;
    }
    __syncthreads();
    const int n = t >> 2, seg = t & 3;
    unsigned short hi[16], lo[16];
    #pragma unroll
    for (int u = 0; u < 16; u++) split2(tile[n][16 * seg + u], hi[u], lo[u]);
    const long base = (long)(mm * 64 + n) * CDIM + kt * 64 + 16 * seg;
    *reinterpret_cast<uint4*>(&wThi[base + 0]) = *reinterpret_cast<uint4*>(&hi[0]);
    *reinterpret_cast<uint4*>(&wThi[base + 8]) = *reinterpret_cast<uint4*>(&hi[8]);
    *reinterpret_cast<uint4*>(&wTlo[base + 0]) = *reinterpret_cast<uint4*>(&lo[0]);
    *reinterpret_cast<uint4*>(&wTlo[base + 8]) = *reinterpret_cast<uint4*>(&lo[8]);
}

// ---------------- fused K/Q/V projection: 1 barrier/chunk pipeline ----------------
// 512 blocks x 256 thr; 32 rows/block; x double-buffered in LDS (chunks of 32 c);
// W fragments register-prefetched one chunk ahead.
__global__ __launch_bounds__(256) void proj_mfma(
    const float* __restrict__ x,
    const unsigned short* __restrict__ wThi, const unsigned short* __restrict__ wTlo,
    unsigned short* __restrict__ khi, unsigned short* __restrict__ klo,
    unsigned short* __restrict__ qhi, unsigned short* __restrict__ qlo,
    unsigned short* __restrict__ vt)
{
    __shared__ __align__(16) unsigned short xh2[2][32 * 40];
    __shared__ __align__(16) unsigned short xl2[2][32 * 40];
    const int t = threadIdx.x;
    const int lane = t & 63, w = t >> 6;
    const int r15 = lane & 15, g = lane >> 4;
    const long rowbase = (long)blockIdx.x * 32;
    const int r0 = t >> 3, c0 = t & 7;
    const float* __restrict__ xrow = &x[(rowbase + r0) * CDIM + 4 * c0];

    long nrow[3];
    #pragma unroll
    for (int nt = 0; nt < 3; nt++) nrow[nt] = (long)(16 * (3 * w + nt) + r15) * CDIM + 8 * g;

    f32x4 acc[2][3];
    #pragma unroll
    for (int mt = 0; mt < 2; mt++)
        #pragma unroll
        for (int nt = 0; nt < 3; nt++) acc[mt][nt] = (f32x4){0.f, 0.f, 0.f, 0.f};

    // prologue: chunk 0 staged, W chunk 0 in regs, x chunk 1 in regs
    float4 xa = *reinterpret_cast<const float4*>(&xrow[0]);
    bf16x8 Wch[3], Wcl[3];
    #pragma unroll
    for (int nt = 0; nt < 3; nt++) {
        Wch[nt] = *reinterpret_cast<const bf16x8*>(&wThi[nrow[nt]]);
        Wcl[nt] = *reinterpret_cast<const bf16x8*>(&wTlo[nrow[nt]]);
    }
    float4 xn = *reinterpret_cast<const float4*>(&xrow[32]);
    {
        ushort4 h4, l4;
        split2(xa.x, h4.x, l4.x); split2(xa.y, h4.y, l4.y);
        split2(xa.z, h4.z, l4.z); split2(xa.w, h4.w, l4.w);
        *reinterpret_cast<ushort4*>(&xh2[0][r0 * 40 + 4 * c0]) = h4;
        *reinterpret_cast<ushort4*>(&xl2[0][r0 * 40 + 4 * c0]) = l4;
    }

    for (int j = 0; j < 32; ++j) {
        __syncthreads();                       // chunk j visible; prior reads drained
        const int buf = j & 1;
        if (j < 31) {                          // stage chunk j+1
            ushort4 h4, l4;
            split2(xn.x, h4.x, l4.x); split2(xn.y, h4.y, l4.y);
            split2(xn.z, h4.z, l4.z); split2(xn.w, h4.w, l4.w);
            *reinterpret_cast<ushort4*>(&xh2[buf ^ 1][r0 * 40 + 4 * c0]) = h4;
            *reinterpret_cast<ushort4*>(&xl2[buf ^ 1][r0 * 40 + 4 * c0]) = l4;
        }
        if (j < 30) xn = *reinterpret_cast<const float4*>(&xrow[(j + 2) * 32]);
        bf16x8 Wnh[3], Wnl[3];
        const int kcn = (j < 31) ? (j + 1) * 32 : j * 32;   // clamp (discarded at j=31)
        #pragma unroll
        for (int nt = 0; nt < 3; nt++) {
            Wnh[nt] = *reinterpret_cast<const bf16x8*>(&wThi[nrow[nt] + kcn]);
            Wnl[nt] = *reinterpret_cast<const bf16x8*>(&wTlo[nrow[nt] + kcn]);
        }
        // compute chunk j
        bf16x8 ah[2], al[2];
        #pragma unroll
        for (int mt = 0; mt < 2; mt++) {
            ah[mt] = *reinterpret_cast<const bf16x8*>(&xh2[buf][(16 * mt + r15) * 40 + 8 * g]);
            al[mt] = *reinterpret_cast<const bf16x8*>(&xl2[buf][(16 * mt + r15) * 40 + 8 * g]);
        }
        #pragma unroll
        for (int nt = 0; nt < 3; nt++)
            #pragma unroll
            for (int mt = 0; mt < 2; mt++) {
                acc[mt][nt] = mfma16(ah[mt], Wch[nt], acc[mt][nt]);
                acc[mt][nt] = mfma16(al[mt], Wch[nt], acc[mt][nt]);
                acc[mt][nt] = mfma16(ah[mt], Wcl[nt], acc[mt][nt]);
            }
        #pragma unroll
        for (int nt = 0; nt < 3; nt++) { Wch[nt] = Wnh[nt]; Wcl[nt] = Wnl[nt]; }
    }

    const int bb = (int)(rowbase >> 11);
    const int trow0 = (int)(rowbase & 2047);
    #pragma unroll
    for (int nt = 0; nt < 3; nt++) {
        const int ntg = 3 * w + nt;
        const int mat = ntg >> 2;
        const int colin = (ntg & 3) * 16 + r15;
        if (mat == 0) {
            #pragma unroll
            for (int mt = 0; mt < 2; mt++)
                #pragma unroll
                for (int reg = 0; reg < 4; reg++) {
                    unsigned short h, l;
                    split2(acc[mt][nt][reg], h, l);
                    const long idx = (rowbase + 16 * mt + 4 * g + reg) * HDIM + colin;
                    khi[idx] = h; klo[idx] = l;
                }
        } else if (mat == 1) {
            #pragma unroll
            for (int mt = 0; mt < 2; mt++)
                #pragma unroll
                for (int reg = 0; reg < 4; reg++) {
                    unsigned short h, l;
                    split2(acc[mt][nt][reg] * 32.0f, h, l);   // fold sqrt(C): exact pow2
                    const long idx = (rowbase + 16 * mt + 4 * g + reg) * HDIM + colin;
                    qhi[idx] = h; qlo[idx] = l;
                }
        } else {
            #pragma unroll
            for (int mt = 0; mt < 2; mt++) {
                ushort4 pk;
                pk.x = f2bf(acc[mt][nt][0]); pk.y = f2bf(acc[mt][nt][1]);
                pk.z = f2bf(acc[mt][nt][2]); pk.w = f2bf(acc[mt][nt][3]);
                const long idx = ((long)bb * 64 + colin) * TSEQ + trow0 + 16 * mt + 4 * g;
                *reinterpret_cast<ushort4*>(&vt[idx]) = pk;
            }
        }
    }
}

// ---------------- attention helpers ----------------
__device__ __forceinline__ void kload8(
    const unsigned short* __restrict__ khi, const unsigned short* __restrict__ klo,
    long keybase, int r15, int g, bf16x8 (&kh)[8], bf16x8 (&kl)[8])
{
    #pragma unroll
    for (int mt = 0; mt < 4; mt++) {
        const long arow = (keybase + 16 * mt + r15) * HDIM + 8 * g;
        #pragma unroll
        for (int ks = 0; ks < 2; ks++) {
            kh[2 * mt + ks] = *reinterpret_cast<const bf16x8*>(&khi[arow + 32 * ks]);
            kl[2 * mt + ks] = *reinterpret_cast<const bf16x8*>(&klo[arow + 32 * ks]);
        }
    }
}

__device__ __forceinline__ void softmax_pv(
    f32x4 (&sc)[4], const bf16x8 (&Vv)[8], int r15, int g,
    unsigned short* __restrict__ p_lds, float& m, float& lsum, f32x4 (&o)[4],
    bool diag, int rem)
{
    float bm = -3e38f;
    #pragma unroll
    for (int mt = 0; mt < 4; mt++)
        if (!diag || mt <= rem)
            bm = fmaxf(bm, fmaxf(fmaxf(sc[mt][0], sc[mt][1]), fmaxf(sc[mt][2], sc[mt][3])));
    bm = fmaxf(bm, __shfl_xor(bm, 16));
    bm = fmaxf(bm, __shfl_xor(bm, 32));
    const float mnew = fmaxf(m, bm);
    const float corr = __expf(m - mnew);
    m = mnew;
    float rs = 0.f;
    #pragma unroll
    for (int mt = 0; mt < 4; mt++) {
        ushort4 pk = {0, 0, 0, 0};
        if (!diag || mt <= rem) {
            const float p0 = __expf(sc[mt][0] - mnew);
            const float p1 = __expf(sc[mt][1] - mnew);
            const float p2 = __expf(sc[mt][2] - mnew);
            const float p3 = __expf(sc[mt][3] - mnew);
            rs += (p0 + p1) + (p2 + p3);
            pk.x = f2bf(p0); pk.y = f2bf(p1); pk.z = f2bf(p2); pk.w = f2bf(p3);
        }
        *reinterpret_cast<ushort4*>(&p_lds[r15 * 72 + 16 * mt + 4 * g]) = pk;
    }
    rs += __shfl_xor(rs, 16);
    rs += __shfl_xor(rs, 32);
    lsum = lsum * corr + rs;
    #pragma unroll
    for (int ht = 0; ht < 4; ht++) o[ht] *= corr;
    #pragma unroll
    for (int ks = 0; ks < 2; ks++) {
        const bf16x8 pb = *reinterpret_cast<const bf16x8*>(&p_lds[r15 * 72 + 32 * ks + 8 * g]);
        #pragma unroll
        for (int ht = 0; ht < 4; ht++) o[ht] = mfma16(Vv[2 * ht + ks], pb, o[ht]);
    }
}

// ---------------- flash attention, split-K partials ----------------
// grid (1024, nsplit); block = 1 wave. Partial (m,l,o) per (q-tile, split).
__global__ __launch_bounds__(64, 3) void attn_part(
    const unsigned short* __restrict__ khi, const unsigned short* __restrict__ klo,
    const unsigned short* __restrict__ qhi, const unsigned short* __restrict__ qlo,
    const unsigned short* __restrict__ vt,
    float* __restrict__ po, float* __restrict__ pm, float* __restrict__ pl, int nsplit)
{
    __shared__ __align__(16) unsigned short p_lds[16 * 72];
    const int l = threadIdx.x;
    const int r15 = l & 15, g = l >> 4;
    const int tile = blockIdx.x, p = blockIdx.y;
    const int b = tile >> 7, i = tile & 127;
    const int n = (i >> 2) + 1;
    const int s = (p * n) / nsplit, e = ((p + 1) * n) / nsplit;
    const int pidx = tile * nsplit + p;
    const long pobase = (long)(pidx * 16 + r15) * 64;

    if (s == e) {   // empty split: write neutral partial
        if (g == 0) { pm[pidx * 16 + r15] = -3e38f; pl[pidx * 16 + r15] = 0.f; }
        const f32x4 z = (f32x4){0.f, 0.f, 0.f, 0.f};
        #pragma unroll
        for (int ht = 0; ht < 4; ht++)
            *reinterpret_cast<f32x4*>(&po[pobase + 16 * ht + 4 * g]) = z;
        return;
    }

    const long bkey = (long)b * TSEQ;
    const long qrow = bkey + 16 * i + r15;
    bf16x8 Qh[2], Ql[2];
    #pragma unroll
    for (int ks = 0; ks < 2; ks++) {
        Qh[ks] = *reinterpret_cast<const bf16x8*>(&qhi[qrow * HDIM + 32 * ks + 8 * g]);
        Ql[ks] = *reinterpret_cast<const bf16x8*>(&qlo[qrow * HDIM + 32 * ks + 8 * g]);
    }

    f32x4 o[4];
    #pragma unroll
    for (int ht = 0; ht < 4; ht++) o[ht] = (f32x4){0.f, 0.f, 0.f, 0.f};
    float m = -3e38f, lsum = 0.f;
    const int lc = i >> 2, rem = i & 3;

    for (int kb = s; kb < e; ++kb) {
        bf16x8 kh[8], kl[8];
        kload8(khi, klo, bkey + (long)kb * 64, r15, g, kh, kl);
        bf16x8 Vv[8];
        #pragma unroll
        for (int ht = 0; ht < 4; ht++)
            #pragma unroll
            for (int ks = 0; ks < 2; ks++)
                Vv[2 * ht + ks] = *reinterpret_cast<const bf16x8*>(
                    &vt[((long)b * 64 + 16 * ht + r15) * TSEQ + kb * 64 + 32 * ks + 8 * g]);

        const bool diag = (kb == lc);
        f32x4 sc[4];
        if (!diag) {
            #pragma unroll
            for (int mt = 0; mt < 4; mt++) {
                f32x4 sv = (f32x4){0.f, 0.f, 0.f, 0.f};
                #pragma unroll
                for (int ks = 0; ks < 2; ks++) {
                    sv = mfma16(kh[2 * mt + ks], Qh[ks], sv);
                    sv = mfma16(kh[2 * mt + ks], Ql[ks], sv);
                    sv = mfma16(kl[2 * mt + ks], Qh[ks], sv);
                }
                sc[mt] = sv;
            }
            softmax_pv(sc, Vv, r15, g, p_lds, m, lsum, o, false, 3);
        } else {
            #pragma unroll
            for (int mt = 0; mt < 4; mt++) {
                f32x4 sv = (f32x4){0.f, 0.f, 0.f, 0.f};
                if (mt <= rem) {
                    #pragma unroll
                    for (int ks = 0; ks < 2; ks++) {
                        sv = mfma16(kh[2 * mt + ks], Qh[ks], sv);
                        sv = mfma16(kh[2 * mt + ks], Ql[ks], sv);
                        sv = mfma16(kl[2 * mt + ks], Qh[ks], sv);
                    }
                    if (mt == rem) {
                        #pragma unroll
                        for (int reg = 0; reg < 4; reg++)
                            if (4 * g + reg > r15) sv[reg] = -1e30f;
                    }
                }
                sc[mt] = sv;
            }
            softmax_pv(sc, Vv, r15, g, p_lds, m, lsum, o, true, rem);
        }
    }

    if (g == 0) { pm[pidx * 16 + r15] = m; pl[pidx * 16 + r15] = lsum; }
    #pragma unroll
    for (int ht = 0; ht < 4; ht++)
        *reinterpret_cast<f32x4*>(&po[pobase + 16 * ht + 4 * g]) = o[ht];
}

// ---------------- combine partials ----------------
__global__ __launch_bounds__(64) void attn_comb(
    const float* __restrict__ po, const float* __restrict__ pm, const float* __restrict__ pl,
    float* __restrict__ out, int nsplit)
{
    const int l = threadIdx.x;
    const int r15 = l & 15, g = l >> 4;
    const int tile = blockIdx.x;
    const int b = tile >> 7, i = tile & 127;

    float M = -3e38f;
    for (int p = 0; p < nsplit; ++p)
        M = fmaxf(M, pm[(tile * nsplit + p) * 16 + r15]);

    float L = 0.f;
    f32x4 acc[4];
    #pragma unroll
    for (int ht = 0; ht < 4; ht++) acc[ht] = (f32x4){0.f, 0.f, 0.f, 0.f};
    for (int p = 0; p < nsplit; ++p) {
        const int pidx = tile * nsplit + p;
        const float wp = __expf(pm[pidx * 16 + r15] - M);
        L += wp * pl[pidx * 16 + r15];
        const long pobase = (long)(pidx * 16 + r15) * 64;
        #pragma unroll
        for (int ht = 0; ht < 4; ht++) {
            const f32x4 ov = *reinterpret_cast<const f32x4*>(&po[pobase + 16 * ht + 4 * g]);
            acc[ht] += wp * ov;
        }
    }
    const float inv = 1.0f / L;
    const long qrow = (long)b * TSEQ + 16 * i + r15;
    #pragma unroll
    for (int ht = 0; ht < 4; ht++) {
        const f32x4 ov = acc[ht] * inv;
        *reinterpret_cast<f32x4*>(&out[qrow * HDIM + 16 * ht + 4 * g]) = ov;
    }
}

extern "C" void kernel_launch(void* const* d_in, const int* in_sizes, int n_in,
                              void* d_out, int out_size, void* d_ws, size_t ws_size,
                              hipStream_t stream) {
    const float* x  = (const float*)d_in[0];
    const float* Wk = (const float*)d_in[1];
    const float* Wq = (const float*)d_in[2];
    const float* Wv = (const float*)d_in[3];
    float* outp = (float*)d_out;

    const size_t SZ = (size_t)NROW * HDIM;
    unsigned short* ws   = (unsigned short*)d_ws;
    unsigned short* khi  = ws;
    unsigned short* klo  = ws + 1 * SZ;
    unsigned short* qhi  = ws + 2 * SZ;
    unsigned short* qlo  = ws + 3 * SZ;
    unsigned short* vt   = ws + 4 * SZ;
    unsigned short* wThi = ws + 5 * SZ;
    unsigned short* wTlo = ws + 5 * SZ + 192 * 1024;

    const size_t base_bytes = (5 * SZ + 2 * 192 * 1024) * sizeof(unsigned short); // 11,272,192
    int nsplit = 4;
    while (nsplit > 1 && base_bytes + (size_t)nsplit * 4325376 > ws_size) nsplit >>= 1;

    float* po = (float*)((char*)d_ws + base_bytes);
    float* pm = po + (size_t)1024 * nsplit * 1024;
    float* pl = pm + (size_t)1024 * nsplit * 16;

    w_prep<<<48, 256, 0, stream>>>(Wk, Wq, Wv, wThi, wTlo);
    proj_mfma<<<512, 256, 0, stream>>>(x, wThi, wTlo, khi, klo, qhi, qlo, vt);
    attn_part<<<dim3(1024, nsplit), 64, 0, stream>>>(khi, klo, qhi, qlo, vt, po, pm, pl, nsplit);
    attn_comb<<<1024, 64, 0, stream>>>(po, pm, pl, outp, nsplit);
}

// Round 5
// 134.047 us; speedup vs baseline: 3.1530x; 1.0286x over previous
//
#include <hip/hip_runtime.h>

#define TSEQ 2048
#define CDIM 1024
#define HDIM 64
#define NROW (8 * 2048)

typedef __attribute__((ext_vector_type(8))) short bf16x8;
typedef __attribute__((ext_vector_type(4))) float f32x4;

__device__ __forceinline__ unsigned short f2bf(float f) {
    unsigned int u = __builtin_bit_cast(unsigned int, f);
    u = (u + 0x7FFFu + ((u >> 16) & 1u)) >> 16;   // RNE, finite inputs only
    return (unsigned short)u;
}
__device__ __forceinline__ float bf2f(unsigned short h) {
    unsigned int u = ((unsigned int)h) << 16;
    return __builtin_bit_cast(float, u);
}
__device__ __forceinline__ void split2(float v, unsigned short& h, unsigned short& l) {
    h = f2bf(v);
    l = f2bf(v - bf2f(h));
}
__device__ __forceinline__ f32x4 mfma16(bf16x8 a, bf16x8 b, f32x4 c) {
    return __builtin_amdgcn_mfma_f32_16x16x32_bf16(a, b, c, 0, 0, 0);
}

// ---------------- W prep: transpose + hi/lo split ----------------
__global__ __launch_bounds__(256) void w_prep(
    const float* __restrict__ Wk, const float* __restrict__ Wq, const float* __restrict__ Wv,
    unsigned short* __restrict__ wThi, unsigned short* __restrict__ wTlo)
{
    __shared__ float tile[64][65];
    const int mm = blockIdx.x >> 4, kt = blockIdx.x & 15;
    const float* __restrict__ W = (mm == 0) ? Wk : (mm == 1) ? Wq : Wv;
    const int t = threadIdx.x;
    #pragma unroll
    for (int s = 0; s < 4; s++) {
        const int f = t + 256 * s;
        const int r = f >> 4, cq = f & 15;
        const float4 wv = *reinterpret_cast<const float4*>(&W[(long)(kt * 64 + r) * HDIM + 4 * cq]);
        tile[4 * cq + 0][r] = wv.x; tile[4 * cq + 1][r] = wv.y;
        tile[4 * cq + 2][r] = wv.z; tile[4 * cq + 3][r] = wv.w;
    }
    __syncthreads();
    const int n = t >> 2, seg = t & 3;
    unsigned short hi[16], lo[16];
    #pragma unroll
    for (int u = 0; u < 16; u++) split2(tile[n][16 * seg + u], hi[u], lo[u]);
    const long base = (long)(mm * 64 + n) * CDIM + kt * 64 + 16 * seg;
    *reinterpret_cast<uint4*>(&wThi[base + 0]) = *reinterpret_cast<uint4*>(&hi[0]);
    *reinterpret_cast<uint4*>(&wThi[base + 8]) = *reinterpret_cast<uint4*>(&hi[8]);
    *reinterpret_cast<uint4*>(&wTlo[base + 0]) = *reinterpret_cast<uint4*>(&lo[0]);
    *reinterpret_cast<uint4*>(&wTlo[base + 8]) = *reinterpret_cast<uint4*>(&lo[8]);
}

// ---------------- fused K/Q/V projection: 1 barrier/chunk pipeline ----------------
// 512 blocks x 256 thr; 32 rows/block; XCD-pinned: batch = blockIdx.x & 7.
// launch_bounds(256,2): VGPR cap 256 -> no spills (round-4 lesson: default cap 64 spilled).
__global__ __launch_bounds__(256, 2) void proj_mfma(
    const float* __restrict__ x,
    const unsigned short* __restrict__ wThi, const unsigned short* __restrict__ wTlo,
    unsigned short* __restrict__ khi, unsigned short* __restrict__ klo,
    unsigned short* __restrict__ qhi, unsigned short* __restrict__ qlo,
    unsigned short* __restrict__ vt)
{
    __shared__ __align__(16) unsigned short xh2[2][32 * 40];
    __shared__ __align__(16) unsigned short xl2[2][32 * 40];
    const int t = threadIdx.x;
    const int lane = t & 63, w = t >> 6;
    const int r15 = lane & 15, g = lane >> 4;
    const int bb8 = blockIdx.x & 7, jj = blockIdx.x >> 3;   // XCD pin: wg_id%8 == batch
    const long rowbase = ((long)bb8 * 64 + jj) * 32;
    const int r0 = t >> 3, c0 = t & 7;
    const float* __restrict__ xrow = &x[(rowbase + r0) * CDIM + 4 * c0];

    long nrow[3];
    #pragma unroll
    for (int nt = 0; nt < 3; nt++) nrow[nt] = (long)(16 * (3 * w + nt) + r15) * CDIM + 8 * g;

    f32x4 acc[2][3];
    #pragma unroll
    for (int mt = 0; mt < 2; mt++)
        #pragma unroll
        for (int nt = 0; nt < 3; nt++) acc[mt][nt] = (f32x4){0.f, 0.f, 0.f, 0.f};

    // prologue: chunk 0 staged, W chunk 0 in regs, x chunk 1 in regs
    float4 xa = *reinterpret_cast<const float4*>(&xrow[0]);
    bf16x8 Wch[3], Wcl[3];
    #pragma unroll
    for (int nt = 0; nt < 3; nt++) {
        Wch[nt] = *reinterpret_cast<const bf16x8*>(&wThi[nrow[nt]]);
        Wcl[nt] = *reinterpret_cast<const bf16x8*>(&wTlo[nrow[nt]]);
    }
    float4 xn = *reinterpret_cast<const float4*>(&xrow[32]);
    {
        ushort4 h4, l4;
        split2(xa.x, h4.x, l4.x); split2(xa.y, h4.y, l4.y);
        split2(xa.z, h4.z, l4.z); split2(xa.w, h4.w, l4.w);
        *reinterpret_cast<ushort4*>(&xh2[0][r0 * 40 + 4 * c0]) = h4;
        *reinterpret_cast<ushort4*>(&xl2[0][r0 * 40 + 4 * c0]) = l4;
    }

    for (int j = 0; j < 32; ++j) {
        __syncthreads();                       // chunk j visible; prior reads drained
        const int buf = j & 1;
        if (j < 31) {                          // stage chunk j+1
            ushort4 h4, l4;
            split2(xn.x, h4.x, l4.x); split2(xn.y, h4.y, l4.y);
            split2(xn.z, h4.z, l4.z); split2(xn.w, h4.w, l4.w);
            *reinterpret_cast<ushort4*>(&xh2[buf ^ 1][r0 * 40 + 4 * c0]) = h4;
            *reinterpret_cast<ushort4*>(&xl2[buf ^ 1][r0 * 40 + 4 * c0]) = l4;
        }
        if (j < 30) xn = *reinterpret_cast<const float4*>(&xrow[(j + 2) * 32]);
        bf16x8 Wnh[3], Wnl[3];
        const int kcn = (j < 31) ? (j + 1) * 32 : j * 32;   // clamp (discarded at j=31)
        #pragma unroll
        for (int nt = 0; nt < 3; nt++) {
            Wnh[nt] = *reinterpret_cast<const bf16x8*>(&wThi[nrow[nt] + kcn]);
            Wnl[nt] = *reinterpret_cast<const bf16x8*>(&wTlo[nrow[nt] + kcn]);
        }
        // compute chunk j
        bf16x8 ah[2], al[2];
        #pragma unroll
        for (int mt = 0; mt < 2; mt++) {
            ah[mt] = *reinterpret_cast<const bf16x8*>(&xh2[buf][(16 * mt + r15) * 40 + 8 * g]);
            al[mt] = *reinterpret_cast<const bf16x8*>(&xl2[buf][(16 * mt + r15) * 40 + 8 * g]);
        }
        #pragma unroll
        for (int nt = 0; nt < 3; nt++)
            #pragma unroll
            for (int mt = 0; mt < 2; mt++) {
                acc[mt][nt] = mfma16(ah[mt], Wch[nt], acc[mt][nt]);
                acc[mt][nt] = mfma16(al[mt], Wch[nt], acc[mt][nt]);
                acc[mt][nt] = mfma16(ah[mt], Wcl[nt], acc[mt][nt]);
            }
        #pragma unroll
        for (int nt = 0; nt < 3; nt++) { Wch[nt] = Wnh[nt]; Wcl[nt] = Wnl[nt]; }
    }

    const int bb = (int)(rowbase >> 11);
    const int trow0 = (int)(rowbase & 2047);
    #pragma unroll
    for (int nt = 0; nt < 3; nt++) {
        const int ntg = 3 * w + nt;
        const int mat = ntg >> 2;
        const int colin = (ntg & 3) * 16 + r15;
        if (mat == 0) {
            #pragma unroll
            for (int mt = 0; mt < 2; mt++)
                #pragma unroll
                for (int reg = 0; reg < 4; reg++) {
                    unsigned short h, l;
                    split2(acc[mt][nt][reg], h, l);
                    const long idx = (rowbase + 16 * mt + 4 * g + reg) * HDIM + colin;
                    khi[idx] = h; klo[idx] = l;
                }
        } else if (mat == 1) {
            #pragma unroll
            for (int mt = 0; mt < 2; mt++)
                #pragma unroll
                for (int reg = 0; reg < 4; reg++) {
                    unsigned short h, l;
                    split2(acc[mt][nt][reg] * 32.0f, h, l);   // fold sqrt(C): exact pow2
                    const long idx = (rowbase + 16 * mt + 4 * g + reg) * HDIM + colin;
                    qhi[idx] = h; qlo[idx] = l;
                }
        } else {
            #pragma unroll
            for (int mt = 0; mt < 2; mt++) {
                ushort4 pk;
                pk.x = f2bf(acc[mt][nt][0]); pk.y = f2bf(acc[mt][nt][1]);
                pk.z = f2bf(acc[mt][nt][2]); pk.w = f2bf(acc[mt][nt][3]);
                const long idx = ((long)bb * 64 + colin) * TSEQ + trow0 + 16 * mt + 4 * g;
                *reinterpret_cast<ushort4*>(&vt[idx]) = pk;
            }
        }
    }
}

// ---------------- flash attention, split-K partials ----------------
// grid (256, nsplit), block 256 thr = 4 waves; wave w owns q-tile i = (x>>3)*4 + w
// of batch b = x&7 (XCD-pinned). Defer-max softmax: no cross-lane ops in steady chunks.
__global__ __launch_bounds__(256, 3) void attn_part(
    const unsigned short* __restrict__ khi, const unsigned short* __restrict__ klo,
    const unsigned short* __restrict__ qhi, const unsigned short* __restrict__ qlo,
    const unsigned short* __restrict__ vt,
    float* __restrict__ po, float* __restrict__ pm, float* __restrict__ pl, int nsplit)
{
    __shared__ __align__(16) unsigned short p_lds4[4][16 * 72];
    const int t = threadIdx.x, w = t >> 6, lane = t & 63;
    const int r15 = lane & 15, g = lane >> 4;
    const int xx = blockIdx.x, p = blockIdx.y;
    const int b = xx & 7, j = xx >> 3;          // XCD pin: wg_id%8 == b
    const int i = j * 4 + w;
    const int tile = b * 128 + i;
    const int n = (i >> 2) + 1;
    const int s = (p * n) / nsplit, e = ((p + 1) * n) / nsplit;
    const int pidx = tile * nsplit + p;
    const long pobase = (long)(pidx * 16 + r15) * 64;
    unsigned short* __restrict__ p_lds = &p_lds4[w][0];

    if (s == e) {   // empty split (no barriers in kernel -> divergent return is safe)
        if (g == 0) { pm[pidx * 16 + r15] = -3e38f; pl[pidx * 16 + r15] = 0.f; }
        const f32x4 z = (f32x4){0.f, 0.f, 0.f, 0.f};
        #pragma unroll
        for (int ht = 0; ht < 4; ht++)
            *reinterpret_cast<f32x4*>(&po[pobase + 16 * ht + 4 * g]) = z;
        return;
    }

    const long bkey = (long)b * TSEQ;
    const long qrow = bkey + 16 * i + r15;
    bf16x8 Qh[2], Ql[2];
    #pragma unroll
    for (int ks = 0; ks < 2; ks++) {
        Qh[ks] = *reinterpret_cast<const bf16x8*>(&qhi[qrow * HDIM + 32 * ks + 8 * g]);
        Ql[ks] = *reinterpret_cast<const bf16x8*>(&qlo[qrow * HDIM + 32 * ks + 8 * g]);
    }

    f32x4 o[4];
    #pragma unroll
    for (int ht = 0; ht < 4; ht++) o[ht] = (f32x4){0.f, 0.f, 0.f, 0.f};
    float m = -3e38f, lsum = 0.f;     // lsum: per-lane partial; lane-reduced in epilogue
    const int lc = i >> 2, rem = i & 3;

    for (int kb = s; kb < e; ++kb) {
        // K loads (needed first), then V (consumed after softmax)
        bf16x8 kh[8], kl[8];
        const long keybase = bkey + (long)kb * 64;
        #pragma unroll
        for (int mt = 0; mt < 4; mt++) {
            const long arow = (keybase + 16 * mt + r15) * HDIM + 8 * g;
            #pragma unroll
            for (int ks = 0; ks < 2; ks++) {
                kh[2 * mt + ks] = *reinterpret_cast<const bf16x8*>(&khi[arow + 32 * ks]);
                kl[2 * mt + ks] = *reinterpret_cast<const bf16x8*>(&klo[arow + 32 * ks]);
            }
        }
        bf16x8 Vv[8];
        #pragma unroll
        for (int ht = 0; ht < 4; ht++)
            #pragma unroll
            for (int ks = 0; ks < 2; ks++)
                Vv[2 * ht + ks] = *reinterpret_cast<const bf16x8*>(
                    &vt[((long)b * 64 + 16 * ht + r15) * TSEQ + kb * 64 + 32 * ks + 8 * g]);

        const bool diagc = (kb == lc);
        f32x4 sc[4];
        #pragma unroll
        for (int mt = 0; mt < 4; mt++) {
            const bool valid = !diagc || (mt <= rem);
            const float init = valid ? 0.f : -1e30f;
            f32x4 sv = (f32x4){init, init, init, init};
            if (valid) {
                #pragma unroll
                for (int ks = 0; ks < 2; ks++) {
                    sv = mfma16(kh[2 * mt + ks], Qh[ks], sv);
                    sv = mfma16(kh[2 * mt + ks], Ql[ks], sv);
                    sv = mfma16(kl[2 * mt + ks], Qh[ks], sv);
                }
                if (diagc && mt == rem) {
                    #pragma unroll
                    for (int reg = 0; reg < 4; reg++)
                        if (4 * g + reg > r15) sv[reg] = -1e30f;
                }
            }
            sc[mt] = sv;
        }

        // defer-max online softmax (THR=8): escalation is rare; first chunk auto-escalates
        float bml = -3e38f;
        #pragma unroll
        for (int mt = 0; mt < 4; mt++)
            bml = fmaxf(bml, fmaxf(fmaxf(sc[mt][0], sc[mt][1]), fmaxf(sc[mt][2], sc[mt][3])));
        if (!__all(bml - m <= 8.0f)) {
            float bm = fmaxf(bml, __shfl_xor(bml, 16));
            bm = fmaxf(bm, __shfl_xor(bm, 32));
            const float mnew = fmaxf(m, bm);
            const float corr = __expf(m - mnew);   // m=-3e38 -> corr=0 (first chunk)
            lsum *= corr;
            #pragma unroll
            for (int ht = 0; ht < 4; ht++) o[ht] *= corr;
            m = mnew;
        }
        #pragma unroll
        for (int mt = 0; mt < 4; mt++) {
            const float p0 = __expf(sc[mt][0] - m);
            const float p1 = __expf(sc[mt][1] - m);
            const float p2 = __expf(sc[mt][2] - m);
            const float p3 = __expf(sc[mt][3] - m);
            lsum += (p0 + p1) + (p2 + p3);
            ushort4 pk;
            pk.x = f2bf(p0); pk.y = f2bf(p1); pk.z = f2bf(p2); pk.w = f2bf(p3);
            *reinterpret_cast<ushort4*>(&p_lds[r15 * 72 + 16 * mt + 4 * g]) = pk;
        }
        // PV (single-wave LDS roundtrip; lgkmcnt ordering suffices)
        #pragma unroll
        for (int ks = 0; ks < 2; ks++) {
            const bf16x8 pb = *reinterpret_cast<const bf16x8*>(&p_lds[r15 * 72 + 32 * ks + 8 * g]);
            #pragma unroll
            for (int ht = 0; ht < 4; ht++) o[ht] = mfma16(Vv[2 * ht + ks], pb, o[ht]);
        }
    }

    // epilogue: lane-reduce l across g-quarters, store partials
    lsum += __shfl_xor(lsum, 16);
    lsum += __shfl_xor(lsum, 32);
    if (g == 0) { pm[pidx * 16 + r15] = m; pl[pidx * 16 + r15] = lsum; }
    #pragma unroll
    for (int ht = 0; ht < 4; ht++)
        *reinterpret_cast<f32x4*>(&po[pobase + 16 * ht + 4 * g]) = o[ht];
}

// ---------------- combine partials ----------------
__global__ __launch_bounds__(64) void attn_comb(
    const float* __restrict__ po, const float* __restrict__ pm, const float* __restrict__ pl,
    float* __restrict__ out, int nsplit)
{
    const int l = threadIdx.x;
    const int r15 = l & 15, g = l >> 4;
    const int b = blockIdx.x & 7;                 // XCD pin matches producer
    const int i = blockIdx.x >> 3;
    const int tile = b * 128 + i;

    float M = -3e38f;
    for (int p = 0; p < nsplit; ++p)
        M = fmaxf(M, pm[(tile * nsplit + p) * 16 + r15]);

    float L = 0.f;
    f32x4 acc[4];
    #pragma unroll
    for (int ht = 0; ht < 4; ht++) acc[ht] = (f32x4){0.f, 0.f, 0.f, 0.f};
    for (int p = 0; p < nsplit; ++p) {
        const int pidx = tile * nsplit + p;
        const float wp = __expf(pm[pidx * 16 + r15] - M);
        L += wp * pl[pidx * 16 + r15];
        const long pobase = (long)(pidx * 16 + r15) * 64;
        #pragma unroll
        for (int ht = 0; ht < 4; ht++) {
            const f32x4 ov = *reinterpret_cast<const f32x4*>(&po[pobase + 16 * ht + 4 * g]);
            acc[ht] += wp * ov;
        }
    }
    const float inv = 1.0f / L;
    const long qrow = (long)b * TSEQ + 16 * i + r15;
    #pragma unroll
    for (int ht = 0; ht < 4; ht++) {
        const f32x4 ov = acc[ht] * inv;
        *reinterpret_cast<f32x4*>(&out[qrow * HDIM + 16 * ht + 4 * g]) = ov;
    }
}

extern "C" void kernel_launch(void* const* d_in, const int* in_sizes, int n_in,
                              void* d_out, int out_size, void* d_ws, size_t ws_size,
                              hipStream_t stream) {
    const float* x  = (const float*)d_in[0];
    const float* Wk = (const float*)d_in[1];
    const float* Wq = (const float*)d_in[2];
    const float* Wv = (const float*)d_in[3];
    float* outp = (float*)d_out;

    const size_t SZ = (size_t)NROW * HDIM;
    unsigned short* ws   = (unsigned short*)d_ws;
    unsigned short* khi  = ws;
    unsigned short* klo  = ws + 1 * SZ;
    unsigned short* qhi  = ws + 2 * SZ;
    unsigned short* qlo  = ws + 3 * SZ;
    unsigned short* vt   = ws + 4 * SZ;
    unsigned short* wThi = ws + 5 * SZ;
    unsigned short* wTlo = ws + 5 * SZ + 192 * 1024;

    const size_t base_bytes = (5 * SZ + 2 * 192 * 1024) * sizeof(unsigned short); // 11,272,192
    int nsplit = 4;
    while (nsplit > 1 && base_bytes + (size_t)nsplit * 4325376 > ws_size) nsplit >>= 1;

    float* po = (float*)((char*)d_ws + base_bytes);
    float* pm = po + (size_t)1024 * nsplit * 1024;
    float* pl = pm + (size_t)1024 * nsplit * 16;

    w_prep<<<48, 256, 0, stream>>>(Wk, Wq, Wv, wThi, wTlo);
    proj_mfma<<<512, 256, 0, stream>>>(x, wThi, wTlo, khi, klo, qhi, qlo, vt);
    attn_part<<<dim3(256, nsplit), 256, 0, stream>>>(khi, klo, qhi, qlo, vt, po, pm, pl, nsplit);
    attn_comb<<<1024, 64, 0, stream>>>(po, pm, pl, outp, nsplit);
}

// Round 6
// 88.903 us; speedup vs baseline: 4.7541x; 1.5078x over previous
//
#include <hip/hip_runtime.h>

#define TSEQ 2048
#define CDIM 1024
#define HDIM 64
#define NROW (8 * 2048)

typedef __attribute__((ext_vector_type(8))) short bf16x8;
typedef __attribute__((ext_vector_type(4))) float f32x4;

__device__ __forceinline__ unsigned short f2bf(float f) {
    unsigned int u = __builtin_bit_cast(unsigned int, f);
    u = (u + 0x7FFFu + ((u >> 16) & 1u)) >> 16;   // RNE, finite inputs only
    return (unsigned short)u;
}
__device__ __forceinline__ float bf2f(unsigned short h) {
    unsigned int u = ((unsigned int)h) << 16;
    return __builtin_bit_cast(float, u);
}
__device__ __forceinline__ void split2(float v, unsigned short& h, unsigned short& l) {
    h = f2bf(v);
    l = f2bf(v - bf2f(h));
}
__device__ __forceinline__ f32x4 mfma16(bf16x8 a, bf16x8 b, f32x4 c) {
    return __builtin_amdgcn_mfma_f32_16x16x32_bf16(a, b, c, 0, 0, 0);
}
// async global->LDS, 16B per lane; dest must be wave-uniform-base + lane*16
__device__ __forceinline__ void gload_lds16(const unsigned short* g, unsigned short* l) {
    __builtin_amdgcn_global_load_lds(
        (const __attribute__((address_space(1))) unsigned int*)(g),
        (__attribute__((address_space(3))) unsigned int*)(l), 16, 0, 0);
}

// ---------------- W prep: transpose + hi/lo split ----------------
__global__ __launch_bounds__(256) void w_prep(
    const float* __restrict__ Wk, const float* __restrict__ Wq, const float* __restrict__ Wv,
    unsigned short* __restrict__ wThi, unsigned short* __restrict__ wTlo)
{
    __shared__ float tile[64][65];
    const int mm = blockIdx.x >> 4, kt = blockIdx.x & 15;
    const float* __restrict__ W = (mm == 0) ? Wk : (mm == 1) ? Wq : Wv;
    const int t = threadIdx.x;
    #pragma unroll
    for (int s = 0; s < 4; s++) {
        const int f = t + 256 * s;
        const int r = f >> 4, cq = f & 15;
        const float4 wv = *reinterpret_cast<const float4*>(&W[(long)(kt * 64 + r) * HDIM + 4 * cq]);
        tile[4 * cq + 0][r] = wv.x; tile[4 * cq + 1][r] = wv.y;
        tile[4 * cq + 2][r] = wv.z; tile[4 * cq + 3][r] = wv.w;
    }
    __syncthreads();
    const int n = t >> 2, seg = t & 3;
    unsigned short hi[16], lo[16];
    #pragma unroll
    for (int u = 0; u < 16; u++) split2(tile[n][16 * seg + u], hi[u], lo[u]);
    const long base = (long)(mm * 64 + n) * CDIM + kt * 64 + 16 * seg;
    *reinterpret_cast<uint4*>(&wThi[base + 0]) = *reinterpret_cast<uint4*>(&hi[0]);
    *reinterpret_cast<uint4*>(&wThi[base + 8]) = *reinterpret_cast<uint4*>(&hi[8]);
    *reinterpret_cast<uint4*>(&wTlo[base + 0]) = *reinterpret_cast<uint4*>(&lo[0]);
    *reinterpret_cast<uint4*>(&wTlo[base + 8]) = *reinterpret_cast<uint4*>(&lo[8]);
}

// ---------------- fused K/Q/V projection (unchanged from round 5) ----------------
__global__ __launch_bounds__(256, 2) void proj_mfma(
    const float* __restrict__ x,
    const unsigned short* __restrict__ wThi, const unsigned short* __restrict__ wTlo,
    unsigned short* __restrict__ khi, unsigned short* __restrict__ klo,
    unsigned short* __restrict__ qhi, unsigned short* __restrict__ qlo,
    unsigned short* __restrict__ vt)
{
    __shared__ __align__(16) unsigned short xh2[2][32 * 40];
    __shared__ __align__(16) unsigned short xl2[2][32 * 40];
    const int t = threadIdx.x;
    const int lane = t & 63, w = t >> 6;
    const int r15 = lane & 15, g = lane >> 4;
    const int bb8 = blockIdx.x & 7, jj = blockIdx.x >> 3;   // XCD pin: wg_id%8 == batch
    const long rowbase = ((long)bb8 * 64 + jj) * 32;
    const int r0 = t >> 3, c0 = t & 7;
    const float* __restrict__ xrow = &x[(rowbase + r0) * CDIM + 4 * c0];

    long nrow[3];
    #pragma unroll
    for (int nt = 0; nt < 3; nt++) nrow[nt] = (long)(16 * (3 * w + nt) + r15) * CDIM + 8 * g;

    f32x4 acc[2][3];
    #pragma unroll
    for (int mt = 0; mt < 2; mt++)
        #pragma unroll
        for (int nt = 0; nt < 3; nt++) acc[mt][nt] = (f32x4){0.f, 0.f, 0.f, 0.f};

    float4 xa = *reinterpret_cast<const float4*>(&xrow[0]);
    bf16x8 Wch[3], Wcl[3];
    #pragma unroll
    for (int nt = 0; nt < 3; nt++) {
        Wch[nt] = *reinterpret_cast<const bf16x8*>(&wThi[nrow[nt]]);
        Wcl[nt] = *reinterpret_cast<const bf16x8*>(&wTlo[nrow[nt]]);
    }
    float4 xn = *reinterpret_cast<const float4*>(&xrow[32]);
    {
        ushort4 h4, l4;
        split2(xa.x, h4.x, l4.x); split2(xa.y, h4.y, l4.y);
        split2(xa.z, h4.z, l4.z); split2(xa.w, h4.w, l4.w);
        *reinterpret_cast<ushort4*>(&xh2[0][r0 * 40 + 4 * c0]) = h4;
        *reinterpret_cast<ushort4*>(&xl2[0][r0 * 40 + 4 * c0]) = l4;
    }

    for (int j = 0; j < 32; ++j) {
        __syncthreads();
        const int buf = j & 1;
        if (j < 31) {
            ushort4 h4, l4;
            split2(xn.x, h4.x, l4.x); split2(xn.y, h4.y, l4.y);
            split2(xn.z, h4.z, l4.z); split2(xn.w, h4.w, l4.w);
            *reinterpret_cast<ushort4*>(&xh2[buf ^ 1][r0 * 40 + 4 * c0]) = h4;
            *reinterpret_cast<ushort4*>(&xl2[buf ^ 1][r0 * 40 + 4 * c0]) = l4;
        }
        if (j < 30) xn = *reinterpret_cast<const float4*>(&xrow[(j + 2) * 32]);
        bf16x8 Wnh[3], Wnl[3];
        const int kcn = (j < 31) ? (j + 1) * 32 : j * 32;
        #pragma unroll
        for (int nt = 0; nt < 3; nt++) {
            Wnh[nt] = *reinterpret_cast<const bf16x8*>(&wThi[nrow[nt] + kcn]);
            Wnl[nt] = *reinterpret_cast<const bf16x8*>(&wTlo[nrow[nt] + kcn]);
        }
        bf16x8 ah[2], al[2];
        #pragma unroll
        for (int mt = 0; mt < 2; mt++) {
            ah[mt] = *reinterpret_cast<const bf16x8*>(&xh2[buf][(16 * mt + r15) * 40 + 8 * g]);
            al[mt] = *reinterpret_cast<const bf16x8*>(&xl2[buf][(16 * mt + r15) * 40 + 8 * g]);
        }
        #pragma unroll
        for (int nt = 0; nt < 3; nt++)
            #pragma unroll
            for (int mt = 0; mt < 2; mt++) {
                acc[mt][nt] = mfma16(ah[mt], Wch[nt], acc[mt][nt]);
                acc[mt][nt] = mfma16(al[mt], Wch[nt], acc[mt][nt]);
                acc[mt][nt] = mfma16(ah[mt], Wcl[nt], acc[mt][nt]);
            }
        #pragma unroll
        for (int nt = 0; nt < 3; nt++) { Wch[nt] = Wnh[nt]; Wcl[nt] = Wnl[nt]; }
    }

    const int bb = (int)(rowbase >> 11);
    const int trow0 = (int)(rowbase & 2047);
    #pragma unroll
    for (int nt = 0; nt < 3; nt++) {
        const int ntg = 3 * w + nt;
        const int mat = ntg >> 2;
        const int colin = (ntg & 3) * 16 + r15;
        if (mat == 0) {
            #pragma unroll
            for (int mt = 0; mt < 2; mt++)
                #pragma unroll
                for (int reg = 0; reg < 4; reg++) {
                    unsigned short h, l;
                    split2(acc[mt][nt][reg], h, l);
                    const long idx = (rowbase + 16 * mt + 4 * g + reg) * HDIM + colin;
                    khi[idx] = h; klo[idx] = l;
                }
        } else if (mat == 1) {
            #pragma unroll
            for (int mt = 0; mt < 2; mt++)
                #pragma unroll
                for (int reg = 0; reg < 4; reg++) {
                    unsigned short h, l;
                    split2(acc[mt][nt][reg] * 32.0f, h, l);   // fold sqrt(C): exact pow2
                    const long idx = (rowbase + 16 * mt + 4 * g + reg) * HDIM + colin;
                    qhi[idx] = h; qlo[idx] = l;
                }
        } else {
            #pragma unroll
            for (int mt = 0; mt < 2; mt++) {
                ushort4 pk;
                pk.x = f2bf(acc[mt][nt][0]); pk.y = f2bf(acc[mt][nt][1]);
                pk.z = f2bf(acc[mt][nt][2]); pk.w = f2bf(acc[mt][nt][3]);
                const long idx = ((long)bb * 64 + colin) * TSEQ + trow0 + 16 * mt + 4 * g;
                *reinterpret_cast<ushort4*>(&vt[idx]) = pk;
            }
        }
    }
}

// ---------------- flash attention: 4-wave block, LDS-staged K/V, split-K ----------------
// Block = one 64-row q-tile x key-range split. K/V chunk (64 keys) staged once per block
// via global_load_lds into double-buffered, XOR-swizzled LDS (swizzle applied at the
// global SOURCE address -> linear dest; ds_read applies the same XOR). 2-phase pipeline.
// Work order: zigzag j pairing so any block grouping has ~constant total work.
__global__ __launch_bounds__(256, 2) void attn_part(
    const unsigned short* __restrict__ khi, const unsigned short* __restrict__ klo,
    const unsigned short* __restrict__ qhi, const unsigned short* __restrict__ qlo,
    const unsigned short* __restrict__ vt,
    float* __restrict__ po, float* __restrict__ pm, float* __restrict__ pl, int nsplit)
{
    __shared__ __align__(16) unsigned short ldsbuf[2][3 * 4096];  // [buf][Khi|Klo|V] 8KB each
    __shared__ __align__(16) unsigned short p_lds4[4][16 * 72];
    const int t = threadIdx.x, w = t >> 6, lane = t & 63;
    const int r15 = lane & 15, g = lane >> 4;
    const int id = blockIdx.x;
    const int b = id & 7;                        // XCD pin
    const int u = id >> 3;
    const int t5 = u & 31, p = u >> 5;
    int j = (t5 & 1) ? 31 - (t5 >> 1) : (t5 >> 1);   // zigzag: consecutive blocks mix heavy/light
    if (p & 1) j = 31 - j;                           // strided groups also mix
    const int n = j + 1;
    const int s = (p * n) / nsplit, e = ((p + 1) * n) / nsplit;
    const int pidx = (b * 32 + j) * nsplit + p;

    if (s >= e) {   // empty split: neutral partial (block-uniform branch)
        const int rr = t >> 2, cq = (t & 3) * 16;
        if ((t & 3) == 0) { pm[pidx * 64 + rr] = -3e38f; pl[pidx * 64 + rr] = 0.f; }
        const f32x4 z = (f32x4){0.f, 0.f, 0.f, 0.f};
        float* dst = &po[((long)pidx * 64 + rr) * 64 + cq];
        #pragma unroll
        for (int q = 0; q < 4; q++) *reinterpret_cast<f32x4*>(dst + 4 * q) = z;
        return;
    }

    // staging geometry: thread t covers 16B slots at LDS bytes t*16 + k*4096, k=0..5
    const int row0 = t >> 3;                               // 0..31
    const int ce = (((t & 7) ^ (row0 & 7)) << 3);          // pre-swizzled source element col
    const long bkey = (long)b * TSEQ;
    const long vrow = ((long)b * 64 + row0) * TSEQ;
    unsigned short* const lbT = &ldsbuf[0][0];

    auto stage = [&](int cur, int kb) {
        unsigned short* lb = lbT + cur * (3 * 4096) + t * 8;
        const long kgo  = (bkey + (long)kb * 64 + row0) * HDIM + ce;
        const long kgo2 = kgo + 32 * HDIM;
        const long vgo  = vrow + (long)kb * 64 + ce;
        const long vgo2 = vgo + 32L * TSEQ;
        gload_lds16(khi + kgo,  lb);
        gload_lds16(khi + kgo2, lb + 2048);
        gload_lds16(klo + kgo,  lb + 4096);
        gload_lds16(klo + kgo2, lb + 6144);
        gload_lds16(vt  + vgo,  lb + 8192);
        gload_lds16(vt  + vgo2, lb + 10240);
    };

    // Q fragments (per wave: q rows 64j + 16w + r15)
    const long qrow = bkey + (long)j * 64 + 16 * w + r15;
    bf16x8 Qh[2], Ql[2];
    #pragma unroll
    for (int ks = 0; ks < 2; ks++) {
        Qh[ks] = *reinterpret_cast<const bf16x8*>(&qhi[qrow * HDIM + 32 * ks + 8 * g]);
        Ql[ks] = *reinterpret_cast<const bf16x8*>(&qlo[qrow * HDIM + 32 * ks + 8 * g]);
    }

    f32x4 o[4];
    #pragma unroll
    for (int ht = 0; ht < 4; ht++) o[ht] = (f32x4){0.f, 0.f, 0.f, 0.f};
    float m = -3e38f, lsum = 0.f;
    unsigned short* const pw = &p_lds4[w][0];
    const int sw = (r15 & 7) << 4;
    const int c0 = ((16 * g) ^ sw) >> 1;          // swizzled ushort col offset, ks=0
    const int c1 = ((16 * g + 64) ^ sw) >> 1;     // ks=1

    stage(0, s);
    __syncthreads();   // compiler drains vmcnt before s_barrier

    for (int kb = s; kb < e; ++kb) {
        const int cur = (kb - s) & 1;
        if (kb + 1 < e) stage(cur ^ 1, kb + 1);   // async prefetch, lands by next barrier
        const unsigned short* Kh = lbT + cur * (3 * 4096);
        const unsigned short* Kl = Kh + 4096;
        const unsigned short* Vb = Kh + 8192;
        const bool diag = (kb == j);

        f32x4 sc[4];
        #pragma unroll
        for (int mt = 0; mt < 4; mt++) {
            const bool valid = !diag || (mt <= w);
            f32x4 sv = valid ? (f32x4){0.f, 0.f, 0.f, 0.f}
                             : (f32x4){-1e30f, -1e30f, -1e30f, -1e30f};
            if (valid) {
                const int rb = (16 * mt + r15) * 64;
                const bf16x8 ah0 = *reinterpret_cast<const bf16x8*>(&Kh[rb + c0]);
                const bf16x8 ah1 = *reinterpret_cast<const bf16x8*>(&Kh[rb + c1]);
                const bf16x8 al0 = *reinterpret_cast<const bf16x8*>(&Kl[rb + c0]);
                const bf16x8 al1 = *reinterpret_cast<const bf16x8*>(&Kl[rb + c1]);
                sv = mfma16(ah0, Qh[0], sv);
                sv = mfma16(ah0, Ql[0], sv);
                sv = mfma16(al0, Qh[0], sv);
                sv = mfma16(ah1, Qh[1], sv);
                sv = mfma16(ah1, Ql[1], sv);
                sv = mfma16(al1, Qh[1], sv);
                if (diag && mt == w) {
                    #pragma unroll
                    for (int reg = 0; reg < 4; reg++)
                        if (4 * g + reg > r15) sv[reg] = -1e30f;
                }
            }
            sc[mt] = sv;
        }

        // defer-max online softmax (THR=8); first chunk auto-escalates (m=-3e38)
        float bml = -3e38f;
        #pragma unroll
        for (int mt = 0; mt < 4; mt++)
            bml = fmaxf(bml, fmaxf(fmaxf(sc[mt][0], sc[mt][1]), fmaxf(sc[mt][2], sc[mt][3])));
        if (!__all(bml - m <= 8.0f)) {
            float bm = fmaxf(bml, __shfl_xor(bml, 16));
            bm = fmaxf(bm, __shfl_xor(bm, 32));
            const float mnew = fmaxf(m, bm);
            const float corr = __expf(m - mnew);
            lsum *= corr;
            #pragma unroll
            for (int ht = 0; ht < 4; ht++) o[ht] *= corr;
            m = mnew;
        }
        #pragma unroll
        for (int mt = 0; mt < 4; mt++) {
            const float p0 = __expf(sc[mt][0] - m);
            const float p1 = __expf(sc[mt][1] - m);
            const float p2 = __expf(sc[mt][2] - m);
            const float p3 = __expf(sc[mt][3] - m);
            lsum += (p0 + p1) + (p2 + p3);
            ushort4 pk;
            pk.x = f2bf(p0); pk.y = f2bf(p1); pk.z = f2bf(p2); pk.w = f2bf(p3);
            *reinterpret_cast<ushort4*>(&pw[r15 * 72 + 16 * mt + 4 * g]) = pk;
        }
        // PV from swizzled V in LDS (p_lds roundtrip ordered by lgkmcnt within the wave)
        #pragma unroll
        for (int ks = 0; ks < 2; ks++) {
            const bf16x8 pb = *reinterpret_cast<const bf16x8*>(&pw[r15 * 72 + 32 * ks + 8 * g]);
            const int cc = ks ? c1 : c0;
            #pragma unroll
            for (int ht = 0; ht < 4; ht++) {
                const bf16x8 av = *reinterpret_cast<const bf16x8*>(&Vb[(16 * ht + r15) * 64 + cc]);
                o[ht] = mfma16(av, pb, o[ht]);
            }
        }
        __syncthreads();   // all reads of buf `cur` done; prefetch into cur^1 landed
    }

    // epilogue
    lsum += __shfl_xor(lsum, 16);
    lsum += __shfl_xor(lsum, 32);
    if (g == 0) { pm[pidx * 64 + 16 * w + r15] = m; pl[pidx * 64 + 16 * w + r15] = lsum; }
    #pragma unroll
    for (int ht = 0; ht < 4; ht++)
        *reinterpret_cast<f32x4*>(&po[((long)pidx * 64 + 16 * w + r15) * 64 + 16 * ht + 4 * g]) = o[ht];
}

// ---------------- combine partials ----------------
__global__ __launch_bounds__(256) void attn_comb(
    const float* __restrict__ po, const float* __restrict__ pm, const float* __restrict__ pl,
    float* __restrict__ out, int nsplit)
{
    const int t = threadIdx.x;
    const int b = blockIdx.x & 7, j = blockIdx.x >> 3;   // XCD pin matches producer
    const int r = t >> 2, cq = (t & 3) * 16;
    const int base = (b * 32 + j) * nsplit;

    float M = -3e38f;
    for (int p = 0; p < nsplit; ++p) M = fmaxf(M, pm[(base + p) * 64 + r]);
    float L = 0.f;
    f32x4 acc[4];
    #pragma unroll
    for (int q = 0; q < 4; q++) acc[q] = (f32x4){0.f, 0.f, 0.f, 0.f};
    for (int p = 0; p < nsplit; ++p) {
        const float wp = __expf(pm[(base + p) * 64 + r] - M);
        L += wp * pl[(base + p) * 64 + r];
        const float* src = &po[((long)(base + p) * 64 + r) * 64 + cq];
        #pragma unroll
        for (int q = 0; q < 4; q++) acc[q] += wp * *reinterpret_cast<const f32x4*>(src + 4 * q);
    }
    const float inv = 1.0f / L;
    float* dst = &out[((long)b * TSEQ + j * 64 + r) * HDIM + cq];
    #pragma unroll
    for (int q = 0; q < 4; q++) *reinterpret_cast<f32x4*>(dst + 4 * q) = acc[q] * inv;
}

extern "C" void kernel_launch(void* const* d_in, const int* in_sizes, int n_in,
                              void* d_out, int out_size, void* d_ws, size_t ws_size,
                              hipStream_t stream) {
    const float* x  = (const float*)d_in[0];
    const float* Wk = (const float*)d_in[1];
    const float* Wq = (const float*)d_in[2];
    const float* Wv = (const float*)d_in[3];
    float* outp = (float*)d_out;

    const size_t SZ = (size_t)NROW * HDIM;
    unsigned short* ws   = (unsigned short*)d_ws;
    unsigned short* khi  = ws;
    unsigned short* klo  = ws + 1 * SZ;
    unsigned short* qhi  = ws + 2 * SZ;
    unsigned short* qlo  = ws + 3 * SZ;
    unsigned short* vt   = ws + 4 * SZ;
    unsigned short* wThi = ws + 5 * SZ;
    unsigned short* wTlo = ws + 5 * SZ + 192 * 1024;

    const size_t base_bytes = (5 * SZ + 2 * 192 * 1024) * sizeof(unsigned short); // 11,272,192
    int nsplit = 4;
    // per split: 256 tiles x (64x64 po + 64 pm + 64 pl) x 4B = 4,325,376 B
    while (nsplit > 1 && base_bytes + (size_t)nsplit * 4325376 > ws_size) nsplit >>= 1;

    float* po = (float*)((char*)d_ws + base_bytes);
    float* pm = po + (size_t)256 * 64 * 64 * nsplit;
    float* pl = pm + (size_t)256 * 64 * nsplit;

    w_prep<<<48, 256, 0, stream>>>(Wk, Wq, Wv, wThi, wTlo);
    proj_mfma<<<512, 256, 0, stream>>>(x, wThi, wTlo, khi, klo, qhi, qlo, vt);
    attn_part<<<dim3(256 * nsplit), 256, 0, stream>>>(khi, klo, qhi, qlo, vt, po, pm, pl, nsplit);
    attn_comb<<<256, 256, 0, stream>>>(po, pm, pl, outp, nsplit);
}

// Round 7
// 77.705 us; speedup vs baseline: 5.4392x; 1.1441x over previous
//
#include <hip/hip_runtime.h>

#define TSEQ 2048
#define CDIM 1024
#define HDIM 64
#define NROW (8 * 2048)

typedef __attribute__((ext_vector_type(8))) short bf16x8;
typedef __attribute__((ext_vector_type(4))) float f32x4;

__device__ __forceinline__ unsigned short f2bf(float f) {
    unsigned int u = __builtin_bit_cast(unsigned int, f);
    u = (u + 0x7FFFu + ((u >> 16) & 1u)) >> 16;   // RNE, finite inputs only
    return (unsigned short)u;
}
__device__ __forceinline__ float bf2f(unsigned short h) {
    unsigned int u = ((unsigned int)h) << 16;
    return __builtin_bit_cast(float, u);
}
__device__ __forceinline__ void split2(float v, unsigned short& h, unsigned short& l) {
    h = f2bf(v);
    l = f2bf(v - bf2f(h));
}
__device__ __forceinline__ f32x4 mfma16(bf16x8 a, bf16x8 b, f32x4 c) {
    return __builtin_amdgcn_mfma_f32_16x16x32_bf16(a, b, c, 0, 0, 0);
}
// async global->LDS, 16B per lane; dest must be wave-uniform-base + lane*16
__device__ __forceinline__ void gload_lds16(const unsigned short* g, unsigned short* l) {
    __builtin_amdgcn_global_load_lds(
        (const __attribute__((address_space(1))) unsigned int*)(g),
        (__attribute__((address_space(3))) unsigned int*)(l), 16, 0, 0);
}

// ---------------- W prep: transpose + hi/lo split ----------------
__global__ __launch_bounds__(256) void w_prep(
    const float* __restrict__ Wk, const float* __restrict__ Wq, const float* __restrict__ Wv,
    unsigned short* __restrict__ wThi, unsigned short* __restrict__ wTlo)
{
    __shared__ float tile[64][65];
    const int mm = blockIdx.x >> 4, kt = blockIdx.x & 15;
    const float* __restrict__ W = (mm == 0) ? Wk : (mm == 1) ? Wq : Wv;
    const int t = threadIdx.x;
    #pragma unroll
    for (int s = 0; s < 4; s++) {
        const int f = t + 256 * s;
        const int r = f >> 4, cq = f & 15;
        const float4 wv = *reinterpret_cast<const float4*>(&W[(long)(kt * 64 + r) * HDIM + 4 * cq]);
        tile[4 * cq + 0][r] = wv.x; tile[4 * cq + 1][r] = wv.y;
        tile[4 * cq + 2][r] = wv.z; tile[4 * cq + 3][r] = wv.w;
    }
    __syncthreads();
    const int n = t >> 2, seg = t & 3;
    unsigned short hi[16], lo[16];
    #pragma unroll
    for (int u = 0; u < 16; u++) split2(tile[n][16 * seg + u], hi[u], lo[u]);
    const long base = (long)(mm * 64 + n) * CDIM + kt * 64 + 16 * seg;
    *reinterpret_cast<uint4*>(&wThi[base + 0]) = *reinterpret_cast<uint4*>(&hi[0]);
    *reinterpret_cast<uint4*>(&wThi[base + 8]) = *reinterpret_cast<uint4*>(&hi[8]);
    *reinterpret_cast<uint4*>(&wTlo[base + 0]) = *reinterpret_cast<uint4*>(&lo[0]);
    *reinterpret_cast<uint4*>(&wTlo[base + 8]) = *reinterpret_cast<uint4*>(&lo[8]);
}

// ---------------- fused K/Q/V projection: LDS-staged W (async), 1 barrier/chunk ----------------
// 512 blocks (=2/CU, one generation) x 256 thr; 32 rows/block; k-chunks of 32.
// W chunk [192][32] hi+lo staged via global_load_lds (cannot be sunk by regalloc — the
// round-6 failure mode where register-prefetched W collapsed to serial L2 loads at VGPR=60).
// Linear LDS dest + source-side XOR swizzle slot^=(row>>1)&3, same XOR on ds_read (2-way banks).
__global__ __launch_bounds__(256, 2) void proj_mfma(
    const float* __restrict__ x,
    const unsigned short* __restrict__ wThi, const unsigned short* __restrict__ wTlo,
    unsigned short* __restrict__ khi, unsigned short* __restrict__ klo,
    unsigned short* __restrict__ qhi, unsigned short* __restrict__ qlo,
    unsigned short* __restrict__ vt)
{
    __shared__ __align__(16) unsigned short wlds[2][2][192 * 32];  // 48 KB: [buf][hi/lo][row*32+c]
    __shared__ __align__(16) unsigned short xlds[2][2][32 * 40];   // 10 KB: padded, VALU-written
    const int t = threadIdx.x;
    const int lane = t & 63, w = t >> 6;
    const int r15 = lane & 15, g = lane >> 4;
    const int bb8 = blockIdx.x & 7, jj = blockIdx.x >> 3;   // XCD pin: wg_id%8 == batch
    const long rowbase = ((long)bb8 * 64 + jj) * 32;
    const int xr = t >> 3, xc = t & 7;
    const float* __restrict__ xrow = &x[(rowbase + xr) * CDIM + 4 * xc];

    // staging geometry (W): thread t, issue q: slot s=t+256q; row=s>>2, phys slot=s&3;
    // logical col = (phys ^ ((row>>1)&3))*8
    int wsrc[3];
    #pragma unroll
    for (int q = 0; q < 3; q++) {
        const int s = t + 256 * q;
        const int row = s >> 2, sl = s & 3;
        wsrc[q] = row * CDIM + (((sl ^ ((row >> 1) & 3))) << 3);
    }
    const int coff = (g ^ ((r15 >> 1) & 3)) << 3;   // read-side swizzled col (ushorts)

    f32x4 acc[2][3];
    #pragma unroll
    for (int mt = 0; mt < 2; mt++)
        #pragma unroll
        for (int nt = 0; nt < 3; nt++) acc[mt][nt] = (f32x4){0.f, 0.f, 0.f, 0.f};

    // ---- prologue: chunk 0 into buf 0; x chunk 1 into reg ----
    float4 xreg = *reinterpret_cast<const float4*>(&xrow[0]);
    {
        ushort4 h4, l4;
        split2(xreg.x, h4.x, l4.x); split2(xreg.y, h4.y, l4.y);
        split2(xreg.z, h4.z, l4.z); split2(xreg.w, h4.w, l4.w);
        *reinterpret_cast<ushort4*>(&xlds[0][0][xr * 40 + 4 * xc]) = h4;
        *reinterpret_cast<ushort4*>(&xlds[0][1][xr * 40 + 4 * xc]) = l4;
    }
    #pragma unroll
    for (int q = 0; q < 3; q++) {
        unsigned short* dst = &wlds[0][0][0] + (t + 256 * q) * 8;
        gload_lds16(&wThi[wsrc[q]], dst);
        gload_lds16(&wTlo[wsrc[q]], dst + 192 * 32);
    }
    xreg = *reinterpret_cast<const float4*>(&xrow[32]);
    __syncthreads();

    for (int j = 0; j < 32; ++j) {
        const int buf = j & 1;
        if (j < 31) {   // stage chunk j+1 into buf^1
            ushort4 h4, l4;
            split2(xreg.x, h4.x, l4.x); split2(xreg.y, h4.y, l4.y);
            split2(xreg.z, h4.z, l4.z); split2(xreg.w, h4.w, l4.w);
            *reinterpret_cast<ushort4*>(&xlds[buf ^ 1][0][xr * 40 + 4 * xc]) = h4;
            *reinterpret_cast<ushort4*>(&xlds[buf ^ 1][1][xr * 40 + 4 * xc]) = l4;
            const int kc = (j + 1) * 32;
            #pragma unroll
            for (int q = 0; q < 3; q++) {
                unsigned short* dst = &wlds[buf ^ 1][0][0] + (t + 256 * q) * 8;
                gload_lds16(&wThi[wsrc[q] + kc], dst);
                gload_lds16(&wTlo[wsrc[q] + kc], dst + 192 * 32);
            }
        }
        if (j < 30) xreg = *reinterpret_cast<const float4*>(&xrow[(j + 2) * 32]);

        // compute chunk j from buf
        bf16x8 ah[2], al[2];
        #pragma unroll
        for (int mt = 0; mt < 2; mt++) {
            ah[mt] = *reinterpret_cast<const bf16x8*>(&xlds[buf][0][(16 * mt + r15) * 40 + 8 * g]);
            al[mt] = *reinterpret_cast<const bf16x8*>(&xlds[buf][1][(16 * mt + r15) * 40 + 8 * g]);
        }
        #pragma unroll
        for (int nt = 0; nt < 3; nt++) {
            const int rown = (3 * w + nt) * 16 + r15;
            const bf16x8 bh = *reinterpret_cast<const bf16x8*>(&wlds[buf][0][rown * 32 + coff]);
            const bf16x8 bl = *reinterpret_cast<const bf16x8*>(&wlds[buf][1][rown * 32 + coff]);
            #pragma unroll
            for (int mt = 0; mt < 2; mt++) {
                acc[mt][nt] = mfma16(ah[mt], bh, acc[mt][nt]);
                acc[mt][nt] = mfma16(al[mt], bh, acc[mt][nt]);
                acc[mt][nt] = mfma16(ah[mt], bl, acc[mt][nt]);
            }
        }
        __syncthreads();   // reads of buf done; staging into buf^1 landed (vmcnt drained)
    }

    const int bb = (int)(rowbase >> 11);
    const int trow0 = (int)(rowbase & 2047);
    #pragma unroll
    for (int nt = 0; nt < 3; nt++) {
        const int ntg = 3 * w + nt;
        const int mat = ntg >> 2;
        const int colin = (ntg & 3) * 16 + r15;
        if (mat == 0) {
            #pragma unroll
            for (int mt = 0; mt < 2; mt++)
                #pragma unroll
                for (int reg = 0; reg < 4; reg++) {
                    unsigned short h, l;
                    split2(acc[mt][nt][reg], h, l);
                    const long idx = (rowbase + 16 * mt + 4 * g + reg) * HDIM + colin;
                    khi[idx] = h; klo[idx] = l;
                }
        } else if (mat == 1) {
            #pragma unroll
            for (int mt = 0; mt < 2; mt++)
                #pragma unroll
                for (int reg = 0; reg < 4; reg++) {
                    unsigned short h, l;
                    split2(acc[mt][nt][reg] * 32.0f, h, l);   // fold sqrt(C): exact pow2
                    const long idx = (rowbase + 16 * mt + 4 * g + reg) * HDIM + colin;
                    qhi[idx] = h; qlo[idx] = l;
                }
        } else {
            #pragma unroll
            for (int mt = 0; mt < 2; mt++) {
                ushort4 pk;
                pk.x = f2bf(acc[mt][nt][0]); pk.y = f2bf(acc[mt][nt][1]);
                pk.z = f2bf(acc[mt][nt][2]); pk.w = f2bf(acc[mt][nt][3]);
                const long idx = ((long)bb * 64 + colin) * TSEQ + trow0 + 16 * mt + 4 * g;
                *reinterpret_cast<ushort4*>(&vt[idx]) = pk;
            }
        }
    }
}

// ---------------- flash attention: 4-wave block, LDS-staged K/V, split-K ----------------
__global__ __launch_bounds__(256, 2) void attn_part(
    const unsigned short* __restrict__ khi, const unsigned short* __restrict__ klo,
    const unsigned short* __restrict__ qhi, const unsigned short* __restrict__ qlo,
    const unsigned short* __restrict__ vt,
    float* __restrict__ po, float* __restrict__ pm, float* __restrict__ pl, int nsplit)
{
    __shared__ __align__(16) unsigned short ldsbuf[2][3 * 4096];  // [buf][Khi|Klo|V] 8KB each
    __shared__ __align__(16) unsigned short p_lds4[4][16 * 72];
    const int t = threadIdx.x, w = t >> 6, lane = t & 63;
    const int r15 = lane & 15, g = lane >> 4;
    const int id = blockIdx.x;
    const int b = id & 7;                        // XCD pin
    const int u = id >> 3;
    const int t5 = u & 31, p = u >> 5;
    int j = (t5 & 1) ? 31 - (t5 >> 1) : (t5 >> 1);   // zigzag load balance
    if (p & 1) j = 31 - j;
    const int n = j + 1;
    const int s = (p * n) / nsplit, e = ((p + 1) * n) / nsplit;
    const int pidx = (b * 32 + j) * nsplit + p;

    if (s >= e) {   // empty split: neutral partial (block-uniform branch)
        const int rr = t >> 2, cq = (t & 3) * 16;
        if ((t & 3) == 0) { pm[pidx * 64 + rr] = -3e38f; pl[pidx * 64 + rr] = 0.f; }
        const f32x4 z = (f32x4){0.f, 0.f, 0.f, 0.f};
        float* dst = &po[((long)pidx * 64 + rr) * 64 + cq];
        #pragma unroll
        for (int q = 0; q < 4; q++) *reinterpret_cast<f32x4*>(dst + 4 * q) = z;
        return;
    }

    const int row0 = t >> 3;
    const int ce = (((t & 7) ^ (row0 & 7)) << 3);          // pre-swizzled source element col
    const long bkey = (long)b * TSEQ;
    const long vrow = ((long)b * 64 + row0) * TSEQ;
    unsigned short* const lbT = &ldsbuf[0][0];

    auto stage = [&](int cur, int kb) {
        unsigned short* lb = lbT + cur * (3 * 4096) + t * 8;
        const long kgo  = (bkey + (long)kb * 64 + row0) * HDIM + ce;
        const long kgo2 = kgo + 32 * HDIM;
        const long vgo  = vrow + (long)kb * 64 + ce;
        const long vgo2 = vgo + 32L * TSEQ;
        gload_lds16(khi + kgo,  lb);
        gload_lds16(khi + kgo2, lb + 2048);
        gload_lds16(klo + kgo,  lb + 4096);
        gload_lds16(klo + kgo2, lb + 6144);
        gload_lds16(vt  + vgo,  lb + 8192);
        gload_lds16(vt  + vgo2, lb + 10240);
    };

    const long qrow = bkey + (long)j * 64 + 16 * w + r15;
    bf16x8 Qh[2], Ql[2];
    #pragma unroll
    for (int ks = 0; ks < 2; ks++) {
        Qh[ks] = *reinterpret_cast<const bf16x8*>(&qhi[qrow * HDIM + 32 * ks + 8 * g]);
        Ql[ks] = *reinterpret_cast<const bf16x8*>(&qlo[qrow * HDIM + 32 * ks + 8 * g]);
    }

    f32x4 o[4];
    #pragma unroll
    for (int ht = 0; ht < 4; ht++) o[ht] = (f32x4){0.f, 0.f, 0.f, 0.f};
    float m = -3e38f, lsum = 0.f;
    unsigned short* const pw = &p_lds4[w][0];
    const int sw = (r15 & 7) << 4;
    const int c0 = ((16 * g) ^ sw) >> 1;
    const int c1 = ((16 * g + 64) ^ sw) >> 1;

    stage(0, s);
    __syncthreads();

    for (int kb = s; kb < e; ++kb) {
        const int cur = (kb - s) & 1;
        if (kb + 1 < e) stage(cur ^ 1, kb + 1);
        const unsigned short* Kh = lbT + cur * (3 * 4096);
        const unsigned short* Kl = Kh + 4096;
        const unsigned short* Vb = Kh + 8192;
        const bool diag = (kb == j);

        f32x4 sc[4];
        #pragma unroll
        for (int mt = 0; mt < 4; mt++) {
            const bool valid = !diag || (mt <= w);
            f32x4 sv = valid ? (f32x4){0.f, 0.f, 0.f, 0.f}
                             : (f32x4){-1e30f, -1e30f, -1e30f, -1e30f};
            if (valid) {
                const int rb = (16 * mt + r15) * 64;
                const bf16x8 ah0 = *reinterpret_cast<const bf16x8*>(&Kh[rb + c0]);
                const bf16x8 ah1 = *reinterpret_cast<const bf16x8*>(&Kh[rb + c1]);
                const bf16x8 al0 = *reinterpret_cast<const bf16x8*>(&Kl[rb + c0]);
                const bf16x8 al1 = *reinterpret_cast<const bf16x8*>(&Kl[rb + c1]);
                sv = mfma16(ah0, Qh[0], sv);
                sv = mfma16(ah0, Ql[0], sv);
                sv = mfma16(al0, Qh[0], sv);
                sv = mfma16(ah1, Qh[1], sv);
                sv = mfma16(ah1, Ql[1], sv);
                sv = mfma16(al1, Qh[1], sv);
                if (diag && mt == w) {
                    #pragma unroll
                    for (int reg = 0; reg < 4; reg++)
                        if (4 * g + reg > r15) sv[reg] = -1e30f;
                }
            }
            sc[mt] = sv;
        }

        float bml = -3e38f;
        #pragma unroll
        for (int mt = 0; mt < 4; mt++)
            bml = fmaxf(bml, fmaxf(fmaxf(sc[mt][0], sc[mt][1]), fmaxf(sc[mt][2], sc[mt][3])));
        if (!__all(bml - m <= 8.0f)) {
            float bm = fmaxf(bml, __shfl_xor(bml, 16));
            bm = fmaxf(bm, __shfl_xor(bm, 32));
            const float mnew = fmaxf(m, bm);
            const float corr = __expf(m - mnew);
            lsum *= corr;
            #pragma unroll
            for (int ht = 0; ht < 4; ht++) o[ht] *= corr;
            m = mnew;
        }
        #pragma unroll
        for (int mt = 0; mt < 4; mt++) {
            const float p0 = __expf(sc[mt][0] - m);
            const float p1 = __expf(sc[mt][1] - m);
            const float p2 = __expf(sc[mt][2] - m);
            const float p3 = __expf(sc[mt][3] - m);
            lsum += (p0 + p1) + (p2 + p3);
            ushort4 pk;
            pk.x = f2bf(p0); pk.y = f2bf(p1); pk.z = f2bf(p2); pk.w = f2bf(p3);
            *reinterpret_cast<ushort4*>(&pw[r15 * 72 + 16 * mt + 4 * g]) = pk;
        }
        #pragma unroll
        for (int ks = 0; ks < 2; ks++) {
            const bf16x8 pb = *reinterpret_cast<const bf16x8*>(&pw[r15 * 72 + 32 * ks + 8 * g]);
            const int cc = ks ? c1 : c0;
            #pragma unroll
            for (int ht = 0; ht < 4; ht++) {
                const bf16x8 av = *reinterpret_cast<const bf16x8*>(&Vb[(16 * ht + r15) * 64 + cc]);
                o[ht] = mfma16(av, pb, o[ht]);
            }
        }
        __syncthreads();
    }

    lsum += __shfl_xor(lsum, 16);
    lsum += __shfl_xor(lsum, 32);
    if (g == 0) { pm[pidx * 64 + 16 * w + r15] = m; pl[pidx * 64 + 16 * w + r15] = lsum; }
    #pragma unroll
    for (int ht = 0; ht < 4; ht++)
        *reinterpret_cast<f32x4*>(&po[((long)pidx * 64 + 16 * w + r15) * 64 + 16 * ht + 4 * g]) = o[ht];
}

// ---------------- combine partials ----------------
__global__ __launch_bounds__(256) void attn_comb(
    const float* __restrict__ po, const float* __restrict__ pm, const float* __restrict__ pl,
    float* __restrict__ out, int nsplit)
{
    const int t = threadIdx.x;
    const int b = blockIdx.x & 7, j = blockIdx.x >> 3;   // XCD pin matches producer
    const int r = t >> 2, cq = (t & 3) * 16;
    const int base = (b * 32 + j) * nsplit;

    float M = -3e38f;
    for (int p = 0; p < nsplit; ++p) M = fmaxf(M, pm[(base + p) * 64 + r]);
    float L = 0.f;
    f32x4 acc[4];
    #pragma unroll
    for (int q = 0; q < 4; q++) acc[q] = (f32x4){0.f, 0.f, 0.f, 0.f};
    for (int p = 0; p < nsplit; ++p) {
        const float wp = __expf(pm[(base + p) * 64 + r] - M);
        L += wp * pl[(base + p) * 64 + r];
        const float* src = &po[((long)(base + p) * 64 + r) * 64 + cq];
        #pragma unroll
        for (int q = 0; q < 4; q++) acc[q] += wp * *reinterpret_cast<const f32x4*>(src + 4 * q);
    }
    const float inv = 1.0f / L;
    float* dst = &out[((long)b * TSEQ + j * 64 + r) * HDIM + cq];
    #pragma unroll
    for (int q = 0; q < 4; q++) *reinterpret_cast<f32x4*>(dst + 4 * q) = acc[q] * inv;
}

extern "C" void kernel_launch(void* const* d_in, const int* in_sizes, int n_in,
                              void* d_out, int out_size, void* d_ws, size_t ws_size,
                              hipStream_t stream) {
    const float* x  = (const float*)d_in[0];
    const float* Wk = (const float*)d_in[1];
    const float* Wq = (const float*)d_in[2];
    const float* Wv = (const float*)d_in[3];
    float* outp = (float*)d_out;

    const size_t SZ = (size_t)NROW * HDIM;
    unsigned short* ws   = (unsigned short*)d_ws;
    unsigned short* khi  = ws;
    unsigned short* klo  = ws + 1 * SZ;
    unsigned short* qhi  = ws + 2 * SZ;
    unsigned short* qlo  = ws + 3 * SZ;
    unsigned short* vt   = ws + 4 * SZ;
    unsigned short* wThi = ws + 5 * SZ;
    unsigned short* wTlo = ws + 5 * SZ + 192 * 1024;

    const size_t base_bytes = (5 * SZ + 2 * 192 * 1024) * sizeof(unsigned short); // 11,272,192
    int nsplit = 4;
    // per split: 256 tiles x (64x64 po + 64 pm + 64 pl) x 4B = 4,325,376 B
    while (nsplit > 1 && base_bytes + (size_t)nsplit * 4325376 > ws_size) nsplit >>= 1;

    float* po = (float*)((char*)d_ws + base_bytes);
    float* pm = po + (size_t)256 * 64 * 64 * nsplit;
    float* pl = pm + (size_t)256 * 64 * nsplit;

    w_prep<<<48, 256, 0, stream>>>(Wk, Wq, Wv, wThi, wTlo);
    proj_mfma<<<512, 256, 0, stream>>>(x, wThi, wTlo, khi, klo, qhi, qlo, vt);
    attn_part<<<dim3(256 * nsplit), 256, 0, stream>>>(khi, klo, qhi, qlo, vt, po, pm, pl, nsplit);
    attn_comb<<<256, 256, 0, stream>>>(po, pm, pl, outp, nsplit);
}

// Round 8
// 72.958 us; speedup vs baseline: 5.7931x; 1.0651x over previous
//
#include <hip/hip_runtime.h>

#define TSEQ 2048
#define CDIM 1024
#define HDIM 64
#define NROW (8 * 2048)

typedef __attribute__((ext_vector_type(8))) short bf16x8;
typedef __attribute__((ext_vector_type(4))) float f32x4;

__device__ __forceinline__ unsigned short f2bf(float f) {
    unsigned int u = __builtin_bit_cast(unsigned int, f);
    u = (u + 0x7FFFu + ((u >> 16) & 1u)) >> 16;   // RNE, finite inputs only
    return (unsigned short)u;
}
__device__ __forceinline__ float bf2f(unsigned short h) {
    unsigned int u = ((unsigned int)h) << 16;
    return __builtin_bit_cast(float, u);
}
__device__ __forceinline__ void split2(float v, unsigned short& h, unsigned short& l) {
    h = f2bf(v);
    l = f2bf(v - bf2f(h));
}
__device__ __forceinline__ f32x4 mfma16(bf16x8 a, bf16x8 b, f32x4 c) {
    return __builtin_amdgcn_mfma_f32_16x16x32_bf16(a, b, c, 0, 0, 0);
}
// async global->LDS, 16B per lane; dest must be wave-uniform-base + lane*16
__device__ __forceinline__ void gload_lds16(const unsigned short* g, unsigned short* l) {
    __builtin_amdgcn_global_load_lds(
        (const __attribute__((address_space(1))) unsigned int*)(g),
        (__attribute__((address_space(3))) unsigned int*)(l), 16, 0, 0);
}
__device__ __forceinline__ void gload_lds16f(const float* g, float* l) {
    __builtin_amdgcn_global_load_lds(
        (const __attribute__((address_space(1))) unsigned int*)(g),
        (__attribute__((address_space(3))) unsigned int*)(l), 16, 0, 0);
}

// ---------------- W prep: transpose + hi/lo split ----------------
__global__ __launch_bounds__(256) void w_prep(
    const float* __restrict__ Wk, const float* __restrict__ Wq, const float* __restrict__ Wv,
    unsigned short* __restrict__ wThi, unsigned short* __restrict__ wTlo)
{
    __shared__ float tile[64][65];
    const int mm = blockIdx.x >> 4, kt = blockIdx.x & 15;
    const float* __restrict__ W = (mm == 0) ? Wk : (mm == 1) ? Wq : Wv;
    const int t = threadIdx.x;
    #pragma unroll
    for (int s = 0; s < 4; s++) {
        const int f = t + 256 * s;
        const int r = f >> 4, cq = f & 15;
        const float4 wv = *reinterpret_cast<const float4*>(&W[(long)(kt * 64 + r) * HDIM + 4 * cq]);
        tile[4 * cq + 0][r] = wv.x; tile[4 * cq + 1][r] = wv.y;
        tile[4 * cq + 2][r] = wv.z; tile[4 * cq + 3][r] = wv.w;
    }
    __syncthreads();
    const int n = t >> 2, seg = t & 3;
    unsigned short hi[16], lo[16];
    #pragma unroll
    for (int u = 0; u < 16; u++) split2(tile[n][16 * seg + u], hi[u], lo[u]);
    const long base = (long)(mm * 64 + n) * CDIM + kt * 64 + 16 * seg;
    *reinterpret_cast<uint4*>(&wThi[base + 0]) = *reinterpret_cast<uint4*>(&hi[0]);
    *reinterpret_cast<uint4*>(&wThi[base + 8]) = *reinterpret_cast<uint4*>(&hi[8]);
    *reinterpret_cast<uint4*>(&wTlo[base + 0]) = *reinterpret_cast<uint4*>(&lo[0]);
    *reinterpret_cast<uint4*>(&wTlo[base + 8]) = *reinterpret_cast<uint4*>(&lo[8]);
}

// ---------------- fused K/Q/V projection: BM=64 BN=192 BK=64, all-async staging ----------------
// 256 blocks x 512 thr (8 waves: wr=w>>2 row-half, wc=w&3 col-quarter). 128 KiB dynamic LDS:
//   wlds [2][2][192*64] bf16 (96 KB)  - W hi/lo, XOR-swizzled slot^=(row&7)
//   xlds [2][64*64]     f32  (32 KB)  - x raw fp32, same swizzle; split hi/lo on read
// No register-staged operands at all (rounds 5/6/7 lesson: regalloc sinks them -> serial loads).
__global__ __launch_bounds__(512, 1) void proj_mfma(
    const float* __restrict__ x,
    const unsigned short* __restrict__ wThi, const unsigned short* __restrict__ wTlo,
    unsigned short* __restrict__ khi, unsigned short* __restrict__ klo,
    unsigned short* __restrict__ qhi, unsigned short* __restrict__ qlo,
    unsigned short* __restrict__ vt)
{
    extern __shared__ __align__(16) unsigned char smem[];
    unsigned short* const wlds = (unsigned short*)smem;            // [buf][hl][row*64+k]
    float* const xlds = (float*)(smem + 2 * 2 * 12288 * 2);        // [buf][row*64+k]

    const int t = threadIdx.x;
    const int lane = t & 63, w = t >> 6;
    const int r15 = lane & 15, g = lane >> 4;
    const int wr = w >> 2, wc = w & 3;
    const int bb8 = blockIdx.x & 7, jj = blockIdx.x >> 3;   // XCD pin: wg%8 == batch
    const long rowbase = (long)bb8 * TSEQ + jj * 64;

    // staging source offsets (pre-swizzled so linear LDS dest + XOR read line up)
    const int xrow = t >> 4, xsl = t & 15;
    const long xsrc0 = (rowbase + xrow) * CDIM + ((xsl ^ (xrow & 7)) << 2);   // +32768 for q=1
    const int wrow = t >> 3, wsl = t & 7;
    const long wsrc0 = (long)wrow * CDIM + (((wsl ^ (wrow & 7))) << 3);       // +65536*q

    f32x4 acc[2][3];
    #pragma unroll
    for (int mt = 0; mt < 2; mt++)
        #pragma unroll
        for (int nt = 0; nt < 3; nt++) acc[mt][nt] = (f32x4){0.f, 0.f, 0.f, 0.f};

    auto stage = [&](int bufn, int kc) {
        float* xd = xlds + bufn * 4096 + t * 4;
        gload_lds16f(&x[xsrc0 + kc], xd);
        gload_lds16f(&x[xsrc0 + 32768 + kc], xd + 2048);
        unsigned short* wd = wlds + bufn * 24576 + t * 8;
        gload_lds16(&wThi[wsrc0 + kc], wd);
        gload_lds16(&wThi[wsrc0 + 65536 + kc], wd + 4096);
        gload_lds16(&wThi[wsrc0 + 131072 + kc], wd + 8192);
        gload_lds16(&wTlo[wsrc0 + kc], wd + 12288);
        gload_lds16(&wTlo[wsrc0 + 65536 + kc], wd + 12288 + 4096);
        gload_lds16(&wTlo[wsrc0 + 131072 + kc], wd + 12288 + 8192);
    };

    stage(0, 0);
    __syncthreads();

    for (int j = 0; j < 16; ++j) {
        const int buf = j & 1;
        if (j < 15) stage(buf ^ 1, (j + 1) * 64);

        const unsigned short* wbase = wlds + buf * 24576;
        const float* xbase = xlds + buf * 4096;

        // x fragments: read fp32 (swizzled), split hi/lo in-register
        bf16x8 ah[2][2], al[2][2];
        #pragma unroll
        for (int mt = 0; mt < 2; mt++) {
            const int rx = 32 * wr + 16 * mt + r15;
            const float* xb = xbase + rx * 64;
            const int r7 = rx & 7;
            #pragma unroll
            for (int ks = 0; ks < 2; ks++) {
                const f32x4 a0 = *reinterpret_cast<const f32x4*>(xb + ((8 * ks + ((2 * g) ^ r7)) << 2));
                const f32x4 a1 = *reinterpret_cast<const f32x4*>(xb + ((8 * ks + ((2 * g + 1) ^ r7)) << 2));
                unsigned short h0,h1,h2,h3,h4,h5,h6,h7, l0,l1,l2,l3,l4,l5,l6,l7;
                split2(a0.x, h0, l0); split2(a0.y, h1, l1); split2(a0.z, h2, l2); split2(a0.w, h3, l3);
                split2(a1.x, h4, l4); split2(a1.y, h5, l5); split2(a1.z, h6, l6); split2(a1.w, h7, l7);
                ah[mt][ks] = (bf16x8){(short)h0,(short)h1,(short)h2,(short)h3,(short)h4,(short)h5,(short)h6,(short)h7};
                al[mt][ks] = (bf16x8){(short)l0,(short)l1,(short)l2,(short)l3,(short)l4,(short)l5,(short)l6,(short)l7};
            }
        }
        // W fragments + MFMA
        #pragma unroll
        for (int nt = 0; nt < 3; nt++) {
            const int rw = (3 * wc + nt) * 16 + r15;
            const unsigned short* wh = wbase + rw * 64;
            const unsigned short* wl = wh + 12288;
            const int r7w = rw & 7;
            #pragma unroll
            for (int ks = 0; ks < 2; ks++) {
                const bf16x8 bh = *reinterpret_cast<const bf16x8*>(wh + (((g + 4 * ks) ^ r7w) << 3));
                const bf16x8 bl = *reinterpret_cast<const bf16x8*>(wl + (((g + 4 * ks) ^ r7w) << 3));
                #pragma unroll
                for (int mt = 0; mt < 2; mt++) {
                    acc[mt][nt] = mfma16(ah[mt][ks], bh, acc[mt][nt]);
                    acc[mt][nt] = mfma16(al[mt][ks], bh, acc[mt][nt]);
                    acc[mt][nt] = mfma16(ah[mt][ks], bl, acc[mt][nt]);
                }
            }
        }
        __syncthreads();   // reads of buf done; prefetch into buf^1 landed (vmcnt drained)
    }

    // epilogue: D(row=32wr+16mt+4g+reg, col=16*(ntg&3)+r15), ntg=3wc+nt; mat=ntg>>2
    #pragma unroll
    for (int nt = 0; nt < 3; nt++) {
        const int ntg = 3 * wc + nt;
        const int mat = ntg >> 2;
        const int colin = (ntg & 3) * 16 + r15;
        #pragma unroll
        for (int mt = 0; mt < 2; mt++) {
            const int rl = 32 * wr + 16 * mt + 4 * g;
            if (mat == 0) {
                #pragma unroll
                for (int reg = 0; reg < 4; reg++) {
                    unsigned short h, l;
                    split2(acc[mt][nt][reg], h, l);
                    const long idx = (rowbase + rl + reg) * HDIM + colin;
                    khi[idx] = h; klo[idx] = l;
                }
            } else if (mat == 1) {
                #pragma unroll
                for (int reg = 0; reg < 4; reg++) {
                    unsigned short h, l;
                    split2(acc[mt][nt][reg] * 32.0f, h, l);   // fold sqrt(C): exact pow2
                    const long idx = (rowbase + rl + reg) * HDIM + colin;
                    qhi[idx] = h; qlo[idx] = l;
                }
            } else {
                ushort4 pk;
                pk.x = f2bf(acc[mt][nt][0]); pk.y = f2bf(acc[mt][nt][1]);
                pk.z = f2bf(acc[mt][nt][2]); pk.w = f2bf(acc[mt][nt][3]);
                const long idx = ((long)bb8 * 64 + colin) * TSEQ + jj * 64 + rl;
                *reinterpret_cast<ushort4*>(&vt[idx]) = pk;
            }
        }
    }
}

// ---------------- flash attention: 4-wave block, LDS-staged K/V, split-K ----------------
__global__ __launch_bounds__(256, 2) void attn_part(
    const unsigned short* __restrict__ khi, const unsigned short* __restrict__ klo,
    const unsigned short* __restrict__ qhi, const unsigned short* __restrict__ qlo,
    const unsigned short* __restrict__ vt,
    float* __restrict__ po, float* __restrict__ pm, float* __restrict__ pl, int nsplit)
{
    __shared__ __align__(16) unsigned short ldsbuf[2][3 * 4096];  // [buf][Khi|Klo|V] 8KB each
    __shared__ __align__(16) unsigned short p_lds4[4][16 * 72];
    const int t = threadIdx.x, w = t >> 6, lane = t & 63;
    const int r15 = lane & 15, g = lane >> 4;
    const int id = blockIdx.x;
    const int b = id & 7;                        // XCD pin
    const int u = id >> 3;
    const int t5 = u & 31, p = u >> 5;
    int j = (t5 & 1) ? 31 - (t5 >> 1) : (t5 >> 1);   // zigzag load balance
    if (p & 1) j = 31 - j;
    const int n = j + 1;
    const int s = (p * n) / nsplit, e = ((p + 1) * n) / nsplit;
    const int pidx = (b * 32 + j) * nsplit + p;

    if (s >= e) {   // empty split: neutral partial (block-uniform branch)
        const int rr = t >> 2, cq = (t & 3) * 16;
        if ((t & 3) == 0) { pm[pidx * 64 + rr] = -3e38f; pl[pidx * 64 + rr] = 0.f; }
        const f32x4 z = (f32x4){0.f, 0.f, 0.f, 0.f};
        float* dst = &po[((long)pidx * 64 + rr) * 64 + cq];
        #pragma unroll
        for (int q = 0; q < 4; q++) *reinterpret_cast<f32x4*>(dst + 4 * q) = z;
        return;
    }

    const int row0 = t >> 3;
    const int ce = (((t & 7) ^ (row0 & 7)) << 3);          // pre-swizzled source element col
    const long bkey = (long)b * TSEQ;
    const long vrow = ((long)b * 64 + row0) * TSEQ;
    unsigned short* const lbT = &ldsbuf[0][0];

    auto stage = [&](int cur, int kb) {
        unsigned short* lb = lbT + cur * (3 * 4096) + t * 8;
        const long kgo  = (bkey + (long)kb * 64 + row0) * HDIM + ce;
        const long kgo2 = kgo + 32 * HDIM;
        const long vgo  = vrow + (long)kb * 64 + ce;
        const long vgo2 = vgo + 32L * TSEQ;
        gload_lds16(khi + kgo,  lb);
        gload_lds16(khi + kgo2, lb + 2048);
        gload_lds16(klo + kgo,  lb + 4096);
        gload_lds16(klo + kgo2, lb + 6144);
        gload_lds16(vt  + vgo,  lb + 8192);
        gload_lds16(vt  + vgo2, lb + 10240);
    };

    const long qrow = bkey + (long)j * 64 + 16 * w + r15;
    bf16x8 Qh[2], Ql[2];
    #pragma unroll
    for (int ks = 0; ks < 2; ks++) {
        Qh[ks] = *reinterpret_cast<const bf16x8*>(&qhi[qrow * HDIM + 32 * ks + 8 * g]);
        Ql[ks] = *reinterpret_cast<const bf16x8*>(&qlo[qrow * HDIM + 32 * ks + 8 * g]);
    }

    f32x4 o[4];
    #pragma unroll
    for (int ht = 0; ht < 4; ht++) o[ht] = (f32x4){0.f, 0.f, 0.f, 0.f};
    float m = -3e38f, lsum = 0.f;
    unsigned short* const pw = &p_lds4[w][0];
    const int sw = (r15 & 7) << 4;
    const int c0 = ((16 * g) ^ sw) >> 1;
    const int c1 = ((16 * g + 64) ^ sw) >> 1;

    stage(0, s);
    __syncthreads();

    for (int kb = s; kb < e; ++kb) {
        const int cur = (kb - s) & 1;
        if (kb + 1 < e) stage(cur ^ 1, kb + 1);
        const unsigned short* Kh = lbT + cur * (3 * 4096);
        const unsigned short* Kl = Kh + 4096;
        const unsigned short* Vb = Kh + 8192;
        const bool diag = (kb == j);

        f32x4 sc[4];
        #pragma unroll
        for (int mt = 0; mt < 4; mt++) {
            const bool valid = !diag || (mt <= w);
            f32x4 sv = valid ? (f32x4){0.f, 0.f, 0.f, 0.f}
                             : (f32x4){-1e30f, -1e30f, -1e30f, -1e30f};
            if (valid) {
                const int rb = (16 * mt + r15) * 64;
                const bf16x8 ah0 = *reinterpret_cast<const bf16x8*>(&Kh[rb + c0]);
                const bf16x8 ah1 = *reinterpret_cast<const bf16x8*>(&Kh[rb + c1]);
                const bf16x8 al0 = *reinterpret_cast<const bf16x8*>(&Kl[rb + c0]);
                const bf16x8 al1 = *reinterpret_cast<const bf16x8*>(&Kl[rb + c1]);
                sv = mfma16(ah0, Qh[0], sv);
                sv = mfma16(ah0, Ql[0], sv);
                sv = mfma16(al0, Qh[0], sv);
                sv = mfma16(ah1, Qh[1], sv);
                sv = mfma16(ah1, Ql[1], sv);
                sv = mfma16(al1, Qh[1], sv);
                if (diag && mt == w) {
                    #pragma unroll
                    for (int reg = 0; reg < 4; reg++)
                        if (4 * g + reg > r15) sv[reg] = -1e30f;
                }
            }
            sc[mt] = sv;
        }

        float bml = -3e38f;
        #pragma unroll
        for (int mt = 0; mt < 4; mt++)
            bml = fmaxf(bml, fmaxf(fmaxf(sc[mt][0], sc[mt][1]), fmaxf(sc[mt][2], sc[mt][3])));
        if (!__all(bml - m <= 8.0f)) {
            float bm = fmaxf(bml, __shfl_xor(bml, 16));
            bm = fmaxf(bm, __shfl_xor(bm, 32));
            const float mnew = fmaxf(m, bm);
            const float corr = __expf(m - mnew);
            lsum *= corr;
            #pragma unroll
            for (int ht = 0; ht < 4; ht++) o[ht] *= corr;
            m = mnew;
        }
        #pragma unroll
        for (int mt = 0; mt < 4; mt++) {
            const float p0 = __expf(sc[mt][0] - m);
            const float p1 = __expf(sc[mt][1] - m);
            const float p2 = __expf(sc[mt][2] - m);
            const float p3 = __expf(sc[mt][3] - m);
            lsum += (p0 + p1) + (p2 + p3);
            ushort4 pk;
            pk.x = f2bf(p0); pk.y = f2bf(p1); pk.z = f2bf(p2); pk.w = f2bf(p3);
            *reinterpret_cast<ushort4*>(&pw[r15 * 72 + 16 * mt + 4 * g]) = pk;
        }
        #pragma unroll
        for (int ks = 0; ks < 2; ks++) {
            const bf16x8 pb = *reinterpret_cast<const bf16x8*>(&pw[r15 * 72 + 32 * ks + 8 * g]);
            const int cc = ks ? c1 : c0;
            #pragma unroll
            for (int ht = 0; ht < 4; ht++) {
                const bf16x8 av = *reinterpret_cast<const bf16x8*>(&Vb[(16 * ht + r15) * 64 + cc]);
                o[ht] = mfma16(av, pb, o[ht]);
            }
        }
        __syncthreads();
    }

    lsum += __shfl_xor(lsum, 16);
    lsum += __shfl_xor(lsum, 32);
    if (g == 0) { pm[pidx * 64 + 16 * w + r15] = m; pl[pidx * 64 + 16 * w + r15] = lsum; }
    #pragma unroll
    for (int ht = 0; ht < 4; ht++)
        *reinterpret_cast<f32x4*>(&po[((long)pidx * 64 + 16 * w + r15) * 64 + 16 * ht + 4 * g]) = o[ht];
}

// ---------------- combine partials ----------------
__global__ __launch_bounds__(256) void attn_comb(
    const float* __restrict__ po, const float* __restrict__ pm, const float* __restrict__ pl,
    float* __restrict__ out, int nsplit)
{
    const int t = threadIdx.x;
    const int b = blockIdx.x & 7, j = blockIdx.x >> 3;   // XCD pin matches producer
    const int r = t >> 2, cq = (t & 3) * 16;
    const int base = (b * 32 + j) * nsplit;

    float M = -3e38f;
    for (int p = 0; p < nsplit; ++p) M = fmaxf(M, pm[(base + p) * 64 + r]);
    float L = 0.f;
    f32x4 acc[4];
    #pragma unroll
    for (int q = 0; q < 4; q++) acc[q] = (f32x4){0.f, 0.f, 0.f, 0.f};
    for (int p = 0; p < nsplit; ++p) {
        const float wp = __expf(pm[(base + p) * 64 + r] - M);
        L += wp * pl[(base + p) * 64 + r];
        const float* src = &po[((long)(base + p) * 64 + r) * 64 + cq];
        #pragma unroll
        for (int q = 0; q < 4; q++) acc[q] += wp * *reinterpret_cast<const f32x4*>(src + 4 * q);
    }
    const float inv = 1.0f / L;
    float* dst = &out[((long)b * TSEQ + j * 64 + r) * HDIM + cq];
    #pragma unroll
    for (int q = 0; q < 4; q++) *reinterpret_cast<f32x4*>(dst + 4 * q) = acc[q] * inv;
}

extern "C" void kernel_launch(void* const* d_in, const int* in_sizes, int n_in,
                              void* d_out, int out_size, void* d_ws, size_t ws_size,
                              hipStream_t stream) {
    const float* x  = (const float*)d_in[0];
    const float* Wk = (const float*)d_in[1];
    const float* Wq = (const float*)d_in[2];
    const float* Wv = (const float*)d_in[3];
    float* outp = (float*)d_out;

    const size_t SZ = (size_t)NROW * HDIM;
    unsigned short* ws   = (unsigned short*)d_ws;
    unsigned short* khi  = ws;
    unsigned short* klo  = ws + 1 * SZ;
    unsigned short* qhi  = ws + 2 * SZ;
    unsigned short* qlo  = ws + 3 * SZ;
    unsigned short* vt   = ws + 4 * SZ;
    unsigned short* wThi = ws + 5 * SZ;
    unsigned short* wTlo = ws + 5 * SZ + 192 * 1024;

    const size_t base_bytes = (5 * SZ + 2 * 192 * 1024) * sizeof(unsigned short); // 11,272,192
    int nsplit = 4;
    // per split: 256 tiles x (64x64 po + 64 pm + 64 pl) x 4B = 4,325,376 B
    while (nsplit > 1 && base_bytes + (size_t)nsplit * 4325376 > ws_size) nsplit >>= 1;

    float* po = (float*)((char*)d_ws + base_bytes);
    float* pm = po + (size_t)256 * 64 * 64 * nsplit;
    float* pl = pm + (size_t)256 * 64 * nsplit;

    w_prep<<<48, 256, 0, stream>>>(Wk, Wq, Wv, wThi, wTlo);
    proj_mfma<<<256, 512, 131072, stream>>>(x, wThi, wTlo, khi, klo, qhi, qlo, vt);
    attn_part<<<dim3(256 * nsplit), 256, 0, stream>>>(khi, klo, qhi, qlo, vt, po, pm, pl, nsplit);
    attn_comb<<<256, 256, 0, stream>>>(po, pm, pl, outp, nsplit);
}